// Round 1
// baseline (992.961 us; speedup 1.0000x reference)
//
#include <hip/hip_runtime.h>
#include <cfloat>

#define HID 240

static inline size_t alignUp(size_t x, size_t a){ return (x + a - 1) / a * a; }

// ---------------- init: deg=1 (self-loop weight), cnt=0 ----------------
__global__ void k_init(float* __restrict__ deg, unsigned* __restrict__ cnt, int N){
    int i = blockIdx.x * blockDim.x + threadIdx.x;
    if (i < N){ deg[i] = 1.0f; cnt[i] = 0u; }
}

// ---------------- degree sum + histogram by destination ----------------
__global__ void k_deg_hist(const int* __restrict__ col, const float* __restrict__ ew,
                           float* __restrict__ deg, unsigned* __restrict__ cnt, int E){
    int e = blockIdx.x * blockDim.x + threadIdx.x;
    if (e < E){
        int c = col[e];
        atomicAdd(&deg[c], ew[e]);
        atomicAdd(&cnt[c], 1u);
    }
}

// ---------------- dis = rsqrt(deg)  (deg >= 1 always) ----------------
__global__ void k_dis(float* __restrict__ deg, int N){
    int i = blockIdx.x * blockDim.x + threadIdx.x;
    if (i < N) deg[i] = rsqrtf(deg[i]);
}

// ---------------- single-block exclusive scan over N bins ----------------
__global__ void k_scan(const unsigned* __restrict__ cnt, unsigned* __restrict__ off,
                       unsigned* __restrict__ cur, int N){
    __shared__ unsigned wsum[16];
    __shared__ unsigned carry;
    int t = threadIdx.x;
    int lane = t & 63, w = t >> 6;
    if (t == 0) carry = 0u;
    __syncthreads();
    for (int base = 0; base < N; base += 1024){
        int i = base + t;
        unsigned v = (i < N) ? cnt[i] : 0u;
        unsigned x = v;
        #pragma unroll
        for (int o = 1; o < 64; o <<= 1){
            unsigned u = __shfl_up(x, (unsigned)o, 64);
            if (lane >= o) x += u;
        }
        if (lane == 63) wsum[w] = x;
        __syncthreads();
        if (t < 16){
            unsigned y = wsum[t];
            #pragma unroll
            for (int o = 1; o < 16; o <<= 1){
                unsigned u = __shfl_up(y, (unsigned)o, 16);
                if (t >= o) y += u;
            }
            wsum[t] = y;
        }
        __syncthreads();
        unsigned wbase = (w > 0) ? wsum[w - 1] : 0u;
        unsigned excl = carry + wbase + x - v;
        if (i < N){ off[i] = excl; cur[i] = excl; }
        __syncthreads();
        if (t == 0) carry += wsum[15];
        __syncthreads();
    }
    if (t == 0) off[N] = carry;
}

// ---------------- scatter edges into CSR-by-destination ----------------
__global__ void k_scatter(const int* __restrict__ row, const int* __restrict__ col,
                          const float* __restrict__ ew, const float* __restrict__ dis,
                          unsigned* __restrict__ cur, int2* __restrict__ sedge, int E){
    int e = blockIdx.x * blockDim.x + threadIdx.x;
    if (e < E){
        int r = row[e], c = col[e];
        float nw = dis[r] * ew[e] * dis[c];
        unsigned p = atomicAdd(&cur[c], 1u);
        sedge[p] = make_int2(r, __float_as_int(nw));
    }
}

// ---------------- layer-1 linear: H = x @ W1   (K=5) ----------------
__global__ __launch_bounds__(256) void k_gemm1(const float* __restrict__ x,
                                               const float* __restrict__ W1,
                                               float* __restrict__ H, int N){
    __shared__ float sW[5 * HID];
    __shared__ float sx[8 * 5];
    int t = threadIdx.x;
    for (int i = t; i < 5 * HID; i += 256) sW[i] = W1[i];
    int n0 = blockIdx.x * 8;
    if (t < 40){
        int node = n0 + t / 5;
        sx[t] = (node < N) ? x[node * 5 + (t % 5)] : 0.0f;
    }
    __syncthreads();
    if (t < HID){
        float w0 = sW[0 * HID + t], w1 = sW[1 * HID + t], w2 = sW[2 * HID + t];
        float w3 = sW[3 * HID + t], w4 = sW[4 * HID + t];
        #pragma unroll
        for (int n = 0; n < 8; n++){
            int node = n0 + n;
            if (node >= N) break;
            const float* xr = sx + n * 5;
            float acc = xr[0] * w0 + xr[1] * w1 + xr[2] * w2 + xr[3] * w3 + xr[4] * w4;
            H[(size_t)node * HID + t] = acc;
        }
    }
}

// ---------------- generic tiled fp32 GEMM: C = A(MxK) @ W(KxNcol) [+bias] ----------------
// BM=64, BN=80, BK=16; 256 threads, 4x5 accumulators per thread. K % 16 == 0 required.
__global__ __launch_bounds__(256) void k_gemm(const float* __restrict__ A,
                                              const float* __restrict__ W,
                                              const float* __restrict__ bias,
                                              float* __restrict__ C,
                                              int M, int K, int Ncol){
    __shared__ float sA[16][64 + 1];
    __shared__ float sB[16][80 + 5];
    int t  = threadIdx.x;
    int m0 = blockIdx.x * 64;
    int n0 = blockIdx.y * 80;
    int tx = t & 15;       // n-group
    int ty = t >> 4;       // m-group
    int row_a = t >> 2;          // 0..63
    int ka    = (t & 3) * 4;     // 0,4,8,12
    int rb = t >> 4;             // 0..15
    int cb = t & 15;             // 0..15

    float acc[4][5];
    #pragma unroll
    for (int i = 0; i < 4; i++)
        #pragma unroll
        for (int j = 0; j < 5; j++) acc[i][j] = 0.0f;

    for (int k0 = 0; k0 < K; k0 += 16){
        float4 av = make_float4(0.f, 0.f, 0.f, 0.f);
        if (m0 + row_a < M)
            av = *(const float4*)(A + (size_t)(m0 + row_a) * K + k0 + ka);
        sA[ka + 0][row_a] = av.x;
        sA[ka + 1][row_a] = av.y;
        sA[ka + 2][row_a] = av.z;
        sA[ka + 3][row_a] = av.w;
        #pragma unroll
        for (int j = 0; j < 5; j++){
            int n = n0 + cb + 16 * j;
            sB[rb][cb + 16 * j] = (n < Ncol) ? W[(size_t)(k0 + rb) * Ncol + n] : 0.0f;
        }
        __syncthreads();
        #pragma unroll
        for (int k = 0; k < 16; k++){
            float a[4], b[5];
            #pragma unroll
            for (int i = 0; i < 4; i++) a[i] = sA[k][ty + 16 * i];
            #pragma unroll
            for (int j = 0; j < 5; j++) b[j] = sB[k][tx + 16 * j];
            #pragma unroll
            for (int i = 0; i < 4; i++)
                #pragma unroll
                for (int j = 0; j < 5; j++) acc[i][j] += a[i] * b[j];
        }
        __syncthreads();
    }
    #pragma unroll
    for (int i = 0; i < 4; i++){
        int m = m0 + ty + 16 * i;
        if (m >= M) continue;
        #pragma unroll
        for (int j = 0; j < 5; j++){
            int n = n0 + tx + 16 * j;
            if (n < Ncol){
                float v = acc[i][j];
                if (bias) v += bias[n];
                C[(size_t)m * Ncol + n] = v;
            }
        }
    }
}

// ---------------- scatter-max aggregation + bias + ReLU (wave per destination) ----------------
__global__ __launch_bounds__(256) void k_agg(const float* __restrict__ H,
                                             const float* __restrict__ dis,
                                             const unsigned* __restrict__ off,
                                             const int2* __restrict__ sedge,
                                             const float* __restrict__ bias,
                                             float* __restrict__ out, int N){
    int d    = blockIdx.x * (blockDim.x >> 6) + (threadIdx.x >> 6);
    int lane = threadIdx.x & 63;
    if (d >= N) return;
    bool act = lane < 60;   // 60 float4 = 240 floats

    float dd = dis[d];
    float sw = dd * dd;     // self-loop norm = dis[d]*1*dis[d]
    float4 m = make_float4(-FLT_MAX, -FLT_MAX, -FLT_MAX, -FLT_MAX);
    if (act){
        float4 h = ((const float4*)(H + (size_t)d * HID))[lane];
        m.x = sw * h.x; m.y = sw * h.y; m.z = sw * h.z; m.w = sw * h.w;
    }
    unsigned p0 = off[d], p1 = off[d + 1];
    unsigned p = p0;
    for (; p + 2 <= p1; p += 2){
        int2 e0 = sedge[p];
        int2 e1 = sedge[p + 1];
        if (act){
            float w0 = __int_as_float(e0.y);
            float w1 = __int_as_float(e1.y);
            float4 g0 = ((const float4*)(H + (size_t)e0.x * HID))[lane];
            float4 g1 = ((const float4*)(H + (size_t)e1.x * HID))[lane];
            m.x = fmaxf(m.x, w0 * g0.x); m.y = fmaxf(m.y, w0 * g0.y);
            m.z = fmaxf(m.z, w0 * g0.z); m.w = fmaxf(m.w, w0 * g0.w);
            m.x = fmaxf(m.x, w1 * g1.x); m.y = fmaxf(m.y, w1 * g1.y);
            m.z = fmaxf(m.z, w1 * g1.z); m.w = fmaxf(m.w, w1 * g1.w);
        }
    }
    if (p < p1){
        int2 e0 = sedge[p];
        if (act){
            float w0 = __int_as_float(e0.y);
            float4 g0 = ((const float4*)(H + (size_t)e0.x * HID))[lane];
            m.x = fmaxf(m.x, w0 * g0.x); m.y = fmaxf(m.y, w0 * g0.y);
            m.z = fmaxf(m.z, w0 * g0.z); m.w = fmaxf(m.w, w0 * g0.w);
        }
    }
    if (act){
        float4 b = ((const float4*)bias)[lane];
        float4 o;
        o.x = fmaxf(m.x + b.x, 0.0f);
        o.y = fmaxf(m.y + b.y, 0.0f);
        o.z = fmaxf(m.z + b.z, 0.0f);
        o.w = fmaxf(m.w + b.w, 0.0f);
        ((float4*)(out + (size_t)d * HID))[lane] = o;
    }
}

extern "C" void kernel_launch(void* const* d_in, const int* in_sizes, int n_in,
                              void* d_out, int out_size, void* d_ws, size_t ws_size,
                              hipStream_t stream){
    const float* x  = (const float*)d_in[0];
    const int*   ei = (const int*)  d_in[1];
    const float* ew = (const float*)d_in[2];
    const float* W1 = (const float*)d_in[3];
    const float* b1 = (const float*)d_in[4];
    const float* W2 = (const float*)d_in[5];
    const float* b2 = (const float*)d_in[6];
    const float* We = (const float*)d_in[7];
    const float* be = (const float*)d_in[8];
    float* out = (float*)d_out;

    const int N = in_sizes[0] / 5;
    const int E = in_sizes[2];
    const int* row = ei;       // sources
    const int* col = ei + E;   // destinations

    // workspace carve-out (~110 MB)
    char* w = (char*)d_ws;
    size_t o = 0;
    auto alloc = [&](size_t bytes) -> void* {
        void* p = w + o;
        o = alignUp(o + bytes, 256);
        return p;
    };
    float*    dis   = (float*)   alloc((size_t)N * 4);
    unsigned* cnt   = (unsigned*)alloc((size_t)N * 4);
    unsigned* off   = (unsigned*)alloc((size_t)(N + 1) * 4);
    unsigned* cur   = (unsigned*)alloc((size_t)N * 4);
    int2*     sedge = (int2*)    alloc((size_t)E * 8);
    float*    bufA  = (float*)   alloc((size_t)N * HID * 4);
    float*    bufB  = (float*)   alloc((size_t)N * HID * 4);
    (void)ws_size; (void)n_in; (void)out_size;

    int bn = (N + 255) / 256;
    int be_ = (E + 255) / 256;

    // graph build (shared by both conv layers: same edges, same weights)
    k_init    <<<bn, 256, 0, stream>>>(dis, cnt, N);
    k_deg_hist<<<be_, 256, 0, stream>>>(col, ew, dis, cnt, E);
    k_dis     <<<bn, 256, 0, stream>>>(dis, N);
    k_scan    <<<1, 1024, 0, stream>>>(cnt, off, cur, N);
    k_scatter <<<be_, 256, 0, stream>>>(row, col, ew, dis, cur, sedge, E);

    // layer 1: lin -> max-agg(+b1,ReLU)
    k_gemm1<<<(N + 7) / 8, 256, 0, stream>>>(x, W1, bufA, N);
    k_agg  <<<(N + 3) / 4, 256, 0, stream>>>(bufA, dis, off, sedge, b1, bufB, N);

    // layer 2: lin -> max-agg(+b2,ReLU)
    dim3 g2((N + 63) / 64, (HID + 79) / 80);
    k_gemm<<<g2, 256, 0, stream>>>(bufB, W2, nullptr, bufA, N, HID, HID);
    k_agg <<<(N + 3) / 4, 256, 0, stream>>>(bufA, dis, off, sedge, b2, bufB, N);

    // readout: out = h @ We + be
    dim3 g3((N + 63) / 64, 1);
    k_gemm<<<g3, 256, 0, stream>>>(bufB, We, be, out, N, HID, 80);
}

// Round 2
// 989.038 us; speedup vs baseline: 1.0040x; 1.0040x over previous
//
#include <hip/hip_runtime.h>
#include <cfloat>

#define HID 240

static inline size_t alignUp(size_t x, size_t a){ return (x + a - 1) / a * a; }

// ---------------- init: deg=1 (self-loop weight), cnt=0 ----------------
__global__ void k_init(float* __restrict__ deg, unsigned* __restrict__ cnt, int N){
    int i = blockIdx.x * blockDim.x + threadIdx.x;
    if (i < N){ deg[i] = 1.0f; cnt[i] = 0u; }
}

// ---------------- degree sum + histogram by destination ----------------
__global__ void k_deg_hist(const int* __restrict__ col, const float* __restrict__ ew,
                           float* __restrict__ deg, unsigned* __restrict__ cnt, int E){
    int e = blockIdx.x * blockDim.x + threadIdx.x;
    if (e < E){
        int c = col[e];
        atomicAdd(&deg[c], ew[e]);
        atomicAdd(&cnt[c], 1u);
    }
}

// ---------------- dis = rsqrt(deg)  (deg >= 1 always) ----------------
__global__ void k_dis(float* __restrict__ deg, int N){
    int i = blockIdx.x * blockDim.x + threadIdx.x;
    if (i < N) deg[i] = rsqrtf(deg[i]);
}

// ---------------- single-block exclusive scan over N bins ----------------
__global__ void k_scan(const unsigned* __restrict__ cnt, unsigned* __restrict__ off,
                       unsigned* __restrict__ cur, int N){
    __shared__ unsigned wsum[16];
    __shared__ unsigned carry;
    int t = threadIdx.x;
    int lane = t & 63, w = t >> 6;
    if (t == 0) carry = 0u;
    __syncthreads();
    for (int base = 0; base < N; base += 1024){
        int i = base + t;
        unsigned v = (i < N) ? cnt[i] : 0u;
        unsigned x = v;
        #pragma unroll
        for (int o = 1; o < 64; o <<= 1){
            unsigned u = __shfl_up(x, (unsigned)o, 64);
            if (lane >= o) x += u;
        }
        if (lane == 63) wsum[w] = x;
        __syncthreads();
        if (t < 16){
            unsigned y = wsum[t];
            #pragma unroll
            for (int o = 1; o < 16; o <<= 1){
                unsigned u = __shfl_up(y, (unsigned)o, 16);
                if (t >= o) y += u;
            }
            wsum[t] = y;
        }
        __syncthreads();
        unsigned wbase = (w > 0) ? wsum[w - 1] : 0u;
        unsigned excl = carry + wbase + x - v;
        if (i < N){ off[i] = excl; cur[i] = excl; }
        __syncthreads();
        if (t == 0) carry += wsum[15];
        __syncthreads();
    }
    if (t == 0) off[N] = carry;
}

// ---------------- scatter edges into CSR-by-destination ----------------
__global__ void k_scatter(const int* __restrict__ row, const int* __restrict__ col,
                          const float* __restrict__ ew, const float* __restrict__ dis,
                          unsigned* __restrict__ cur, int2* __restrict__ sedge, int E){
    int e = blockIdx.x * blockDim.x + threadIdx.x;
    if (e < E){
        int r = row[e], c = col[e];
        float nw = dis[r] * ew[e] * dis[c];
        unsigned p = atomicAdd(&cur[c], 1u);
        sedge[p] = make_int2(r, __float_as_int(nw));
    }
}

// ---------------- fused layer-1: max-agg of norm*(x[src]@W1), +b1, ReLU ----------------
// Rank-5 trick: gather x[src] (20 B) instead of h[src] (960 B). W1 columns in regs.
// One wave per destination; lane l owns features 4l..4l+3 (l<60).
__global__ __launch_bounds__(256) void k_agg1(const float* __restrict__ x,
                                              const float* __restrict__ W1,
                                              const float* __restrict__ dis,
                                              const unsigned* __restrict__ off,
                                              const int2* __restrict__ sedge,
                                              const float* __restrict__ bias,
                                              float* __restrict__ out, int N){
    int d    = blockIdx.x * 4 + (threadIdx.x >> 6);
    int lane = threadIdx.x & 63;
    bool act = lane < 60;
    int f0 = lane * 4;

    float wreg[5][4];
    #pragma unroll
    for (int k = 0; k < 5; k++)
        #pragma unroll
        for (int j = 0; j < 4; j++)
            wreg[k][j] = act ? W1[k * HID + f0 + j] : 0.0f;

    if (d >= N) return;

    float dd = dis[d];
    float sw = dd * dd;                    // self-loop norm
    const float* xr = x + (size_t)d * 5;
    float t0 = sw * xr[0], t1 = sw * xr[1], t2 = sw * xr[2], t3 = sw * xr[3], t4 = sw * xr[4];
    float m[4];
    #pragma unroll
    for (int j = 0; j < 4; j++)
        m[j] = t0*wreg[0][j] + t1*wreg[1][j] + t2*wreg[2][j] + t3*wreg[3][j] + t4*wreg[4][j];

    unsigned p0 = off[d], p1 = off[d + 1];
    unsigned p = p0;
    for (; p + 4 <= p1; p += 4){
        int2 e0 = sedge[p], e1 = sedge[p+1], e2 = sedge[p+2], e3 = sedge[p+3];
        const float* s0 = x + (size_t)e0.x * 5;
        const float* s1 = x + (size_t)e1.x * 5;
        const float* s2 = x + (size_t)e2.x * 5;
        const float* s3 = x + (size_t)e3.x * 5;
        float a0[5], a1[5], a2[5], a3[5];
        #pragma unroll
        for (int k = 0; k < 5; k++){ a0[k]=s0[k]; a1[k]=s1[k]; a2[k]=s2[k]; a3[k]=s3[k]; }
        float w0 = __int_as_float(e0.y), w1 = __int_as_float(e1.y);
        float w2 = __int_as_float(e2.y), w3 = __int_as_float(e3.y);
        #pragma unroll
        for (int k = 0; k < 5; k++){ a0[k]*=w0; a1[k]*=w1; a2[k]*=w2; a3[k]*=w3; }
        #pragma unroll
        for (int j = 0; j < 4; j++){
            float v0 = a0[0]*wreg[0][j]+a0[1]*wreg[1][j]+a0[2]*wreg[2][j]+a0[3]*wreg[3][j]+a0[4]*wreg[4][j];
            float v1 = a1[0]*wreg[0][j]+a1[1]*wreg[1][j]+a1[2]*wreg[2][j]+a1[3]*wreg[3][j]+a1[4]*wreg[4][j];
            float v2 = a2[0]*wreg[0][j]+a2[1]*wreg[1][j]+a2[2]*wreg[2][j]+a2[3]*wreg[3][j]+a2[4]*wreg[4][j];
            float v3 = a3[0]*wreg[0][j]+a3[1]*wreg[1][j]+a3[2]*wreg[2][j]+a3[3]*wreg[3][j]+a3[4]*wreg[4][j];
            m[j] = fmaxf(m[j], fmaxf(fmaxf(v0, v1), fmaxf(v2, v3)));
        }
    }
    for (; p < p1; p++){
        int2 e0 = sedge[p];
        const float* s0 = x + (size_t)e0.x * 5;
        float w0 = __int_as_float(e0.y);
        float a0[5];
        #pragma unroll
        for (int k = 0; k < 5; k++) a0[k] = w0 * s0[k];
        #pragma unroll
        for (int j = 0; j < 4; j++){
            float v0 = a0[0]*wreg[0][j]+a0[1]*wreg[1][j]+a0[2]*wreg[2][j]+a0[3]*wreg[3][j]+a0[4]*wreg[4][j];
            m[j] = fmaxf(m[j], v0);
        }
    }
    if (act){
        float4 b = *(const float4*)(bias + f0);
        float4 o;
        o.x = fmaxf(m[0] + b.x, 0.0f);
        o.y = fmaxf(m[1] + b.y, 0.0f);
        o.z = fmaxf(m[2] + b.z, 0.0f);
        o.w = fmaxf(m[3] + b.w, 0.0f);
        *(float4*)(out + (size_t)d * HID + f0) = o;
    }
}

// ---------------- generic tiled fp32 GEMM: C = A(MxK) @ W(KxNcol) [+bias] ----------------
// BM=64, BN=80, BK=16; 256 threads, 4x5 accumulators. K % 16 == 0 required.
// CHUNKED: store C into chunk-plane layout Hc[n/60][m][n%60] (for L2-friendly gather).
template <bool CHUNKED>
__global__ __launch_bounds__(256) void k_gemm(const float* __restrict__ A,
                                              const float* __restrict__ W,
                                              const float* __restrict__ bias,
                                              float* __restrict__ C,
                                              int M, int K, int Ncol){
    __shared__ float sA[16][64 + 1];
    __shared__ float sB[16][80 + 5];
    int t  = threadIdx.x;
    int m0 = blockIdx.x * 64;
    int n0 = blockIdx.y * 80;
    int tx = t & 15;
    int ty = t >> 4;
    int row_a = t >> 2;
    int ka    = (t & 3) * 4;
    int rb = t >> 4;
    int cb = t & 15;

    float acc[4][5];
    #pragma unroll
    for (int i = 0; i < 4; i++)
        #pragma unroll
        for (int j = 0; j < 5; j++) acc[i][j] = 0.0f;

    for (int k0 = 0; k0 < K; k0 += 16){
        float4 av = make_float4(0.f, 0.f, 0.f, 0.f);
        if (m0 + row_a < M)
            av = *(const float4*)(A + (size_t)(m0 + row_a) * K + k0 + ka);
        sA[ka + 0][row_a] = av.x;
        sA[ka + 1][row_a] = av.y;
        sA[ka + 2][row_a] = av.z;
        sA[ka + 3][row_a] = av.w;
        #pragma unroll
        for (int j = 0; j < 5; j++){
            int n = n0 + cb + 16 * j;
            sB[rb][cb + 16 * j] = (n < Ncol) ? W[(size_t)(k0 + rb) * Ncol + n] : 0.0f;
        }
        __syncthreads();
        #pragma unroll
        for (int k = 0; k < 16; k++){
            float a[4], b[5];
            #pragma unroll
            for (int i = 0; i < 4; i++) a[i] = sA[k][ty + 16 * i];
            #pragma unroll
            for (int j = 0; j < 5; j++) b[j] = sB[k][tx + 16 * j];
            #pragma unroll
            for (int i = 0; i < 4; i++)
                #pragma unroll
                for (int j = 0; j < 5; j++) acc[i][j] += a[i] * b[j];
        }
        __syncthreads();
    }
    #pragma unroll
    for (int i = 0; i < 4; i++){
        int m = m0 + ty + 16 * i;
        if (m >= M) continue;
        #pragma unroll
        for (int j = 0; j < 5; j++){
            int n = n0 + tx + 16 * j;
            if (n < Ncol){
                float v = acc[i][j];
                if (bias) v += bias[n];
                if (CHUNKED){
                    int g = n / 60, l = n - 60 * g;
                    C[((size_t)g * M + m) * 60 + l] = v;
                } else {
                    C[(size_t)m * Ncol + n] = v;
                }
            }
        }
    }
}

// ---------------- layer-2 scatter-max from chunk planes, +bias, ReLU ----------------
// grid.y = feature group g (0..3); plane = Hc + g*N*60; lane l<60 owns feature 60g+l.
__global__ __launch_bounds__(256) void k_agg2(const float* __restrict__ Hc,
                                              const float* __restrict__ dis,
                                              const unsigned* __restrict__ off,
                                              const int2* __restrict__ sedge,
                                              const float* __restrict__ bias,
                                              float* __restrict__ out, int N){
    int d    = blockIdx.x * 4 + (threadIdx.x >> 6);
    int g    = blockIdx.y;
    int lane = threadIdx.x & 63;
    if (d >= N) return;
    bool act = lane < 60;
    const float* plane = Hc + (size_t)g * N * 60;

    float dd = dis[d];
    float sw = dd * dd;
    float m = -FLT_MAX;
    if (act) m = sw * plane[(size_t)d * 60 + lane];

    unsigned p0 = off[d], p1 = off[d + 1];
    unsigned p = p0;
    for (; p + 4 <= p1; p += 4){
        int2 e0 = sedge[p], e1 = sedge[p+1], e2 = sedge[p+2], e3 = sedge[p+3];
        if (act){
            float v0 = plane[(size_t)e0.x * 60 + lane];
            float v1 = plane[(size_t)e1.x * 60 + lane];
            float v2 = plane[(size_t)e2.x * 60 + lane];
            float v3 = plane[(size_t)e3.x * 60 + lane];
            v0 *= __int_as_float(e0.y);
            v1 *= __int_as_float(e1.y);
            v2 *= __int_as_float(e2.y);
            v3 *= __int_as_float(e3.y);
            m = fmaxf(m, fmaxf(fmaxf(v0, v1), fmaxf(v2, v3)));
        }
    }
    for (; p < p1; p++){
        int2 e0 = sedge[p];
        if (act){
            float v0 = plane[(size_t)e0.x * 60 + lane];
            m = fmaxf(m, __int_as_float(e0.y) * v0);
        }
    }
    if (act){
        int f = 60 * g + lane;
        out[(size_t)d * HID + f] = fmaxf(m + bias[f], 0.0f);
    }
}

extern "C" void kernel_launch(void* const* d_in, const int* in_sizes, int n_in,
                              void* d_out, int out_size, void* d_ws, size_t ws_size,
                              hipStream_t stream){
    const float* x  = (const float*)d_in[0];
    const int*   ei = (const int*)  d_in[1];
    const float* ew = (const float*)d_in[2];
    const float* W1 = (const float*)d_in[3];
    const float* b1 = (const float*)d_in[4];
    const float* W2 = (const float*)d_in[5];
    const float* b2 = (const float*)d_in[6];
    const float* We = (const float*)d_in[7];
    const float* be = (const float*)d_in[8];
    float* out = (float*)d_out;

    const int N = in_sizes[0] / 5;
    const int E = in_sizes[2];
    const int* row = ei;       // sources
    const int* col = ei + E;   // destinations

    char* w = (char*)d_ws;
    size_t o = 0;
    auto alloc = [&](size_t bytes) -> void* {
        void* p = w + o;
        o = alignUp(o + bytes, 256);
        return p;
    };
    float*    dis   = (float*)   alloc((size_t)N * 4);
    unsigned* cnt   = (unsigned*)alloc((size_t)N * 4);
    unsigned* off   = (unsigned*)alloc((size_t)(N + 1) * 4);
    unsigned* cur   = (unsigned*)alloc((size_t)N * 4);
    int2*     sedge = (int2*)    alloc((size_t)E * 8);
    float*    Hc    = (float*)   alloc((size_t)4 * N * 60 * 4);  // chunk planes, 48 MB
    float*    bufB  = (float*)   alloc((size_t)N * HID * 4);     // 48 MB
    (void)ws_size; (void)n_in; (void)out_size;

    int bn = (N + 255) / 256;
    int be_ = (E + 255) / 256;

    // graph build (shared by both conv layers)
    k_init    <<<bn, 256, 0, stream>>>(dis, cnt, N);
    k_deg_hist<<<be_, 256, 0, stream>>>(col, ew, dis, cnt, E);
    k_dis     <<<bn, 256, 0, stream>>>(dis, N);
    k_scan    <<<1, 1024, 0, stream>>>(cnt, off, cur, N);
    k_scatter <<<be_, 256, 0, stream>>>(row, col, ew, dis, cur, sedge, E);

    // layer 1: fused rank-5 linear + max-agg + b1 + ReLU
    k_agg1<<<(N + 3) / 4, 256, 0, stream>>>(x, W1, dis, off, sedge, b1, bufB, N);

    // layer 2: GEMM into chunk planes, then grouped max-agg + b2 + ReLU
    dim3 g2((N + 63) / 64, (HID + 79) / 80);
    k_gemm<true><<<g2, 256, 0, stream>>>(bufB, W2, nullptr, Hc, N, HID, HID);
    dim3 ga((N + 3) / 4, 4);
    k_agg2<<<ga, 256, 0, stream>>>(Hc, dis, off, sedge, b2, bufB, N);

    // readout: out = h @ We + be
    dim3 g3((N + 63) / 64, 1);
    k_gemm<false><<<g3, 256, 0, stream>>>(bufB, We, be, out, N, HID, 80);
}

// Round 3
// 876.972 us; speedup vs baseline: 1.1323x; 1.1278x over previous
//
#include <hip/hip_runtime.h>
#include <cfloat>

#define HID 240

static inline size_t alignUp(size_t x, size_t a){ return (x + a - 1) / a * a; }

// ---------------- init: deg=1 (self-loop weight), cnt=0 ----------------
__global__ void k_init(float* __restrict__ deg, unsigned* __restrict__ cnt, int N){
    int i = blockIdx.x * blockDim.x + threadIdx.x;
    if (i < N){ deg[i] = 1.0f; cnt[i] = 0u; }
}

// ---------------- degree sum + histogram by destination ----------------
__global__ void k_deg_hist(const int* __restrict__ col, const float* __restrict__ ew,
                           float* __restrict__ deg, unsigned* __restrict__ cnt, int E){
    int e = blockIdx.x * blockDim.x + threadIdx.x;
    if (e < E){
        int c = col[e];
        atomicAdd(&deg[c], ew[e]);
        atomicAdd(&cnt[c], 1u);
    }
}

// ---------------- dis = rsqrt(deg)  (deg >= 1 always) ----------------
__global__ void k_dis(float* __restrict__ deg, int N){
    int i = blockIdx.x * blockDim.x + threadIdx.x;
    if (i < N) deg[i] = rsqrtf(deg[i]);
}

// ---------------- single-block exclusive scan over N bins ----------------
__global__ void k_scan(const unsigned* __restrict__ cnt, unsigned* __restrict__ off,
                       unsigned* __restrict__ cur, int N){
    __shared__ unsigned wsum[16];
    __shared__ unsigned carry;
    int t = threadIdx.x;
    int lane = t & 63, w = t >> 6;
    if (t == 0) carry = 0u;
    __syncthreads();
    for (int base = 0; base < N; base += 1024){
        int i = base + t;
        unsigned v = (i < N) ? cnt[i] : 0u;
        unsigned x = v;
        #pragma unroll
        for (int o = 1; o < 64; o <<= 1){
            unsigned u = __shfl_up(x, (unsigned)o, 64);
            if (lane >= o) x += u;
        }
        if (lane == 63) wsum[w] = x;
        __syncthreads();
        if (t < 16){
            unsigned y = wsum[t];
            #pragma unroll
            for (int o = 1; o < 16; o <<= 1){
                unsigned u = __shfl_up(y, (unsigned)o, 16);
                if (t >= o) y += u;
            }
            wsum[t] = y;
        }
        __syncthreads();
        unsigned wbase = (w > 0) ? wsum[w - 1] : 0u;
        unsigned excl = carry + wbase + x - v;
        if (i < N){ off[i] = excl; cur[i] = excl; }
        __syncthreads();
        if (t == 0) carry += wsum[15];
        __syncthreads();
    }
    if (t == 0) off[N] = carry;
}

// ---------------- scatter edges into CSR-by-destination ----------------
__global__ void k_scatter(const int* __restrict__ row, const int* __restrict__ col,
                          const float* __restrict__ ew, const float* __restrict__ dis,
                          unsigned* __restrict__ cur, int2* __restrict__ sedge, int E){
    int e = blockIdx.x * blockDim.x + threadIdx.x;
    if (e < E){
        int r = row[e], c = col[e];
        float nw = dis[r] * ew[e] * dis[c];
        unsigned p = atomicAdd(&cur[c], 1u);
        sedge[p] = make_int2(r, __float_as_int(nw));
    }
}

// ---------------- fused layer-1: max-agg of norm*(x[src]@W1), +b1, ReLU ----------------
// Rank-5 trick: gather x[src] (20 B) instead of h[src] (960 B). W1 columns in regs.
// One wave per destination; lane l owns features 4l..4l+3 (l<60).
__global__ __launch_bounds__(256) void k_agg1(const float* __restrict__ x,
                                              const float* __restrict__ W1,
                                              const float* __restrict__ dis,
                                              const unsigned* __restrict__ off,
                                              const int2* __restrict__ sedge,
                                              const float* __restrict__ bias,
                                              float* __restrict__ out, int N){
    int d    = blockIdx.x * 4 + (threadIdx.x >> 6);
    int lane = threadIdx.x & 63;
    bool act = lane < 60;
    int f0 = lane * 4;

    float wreg[5][4];
    #pragma unroll
    for (int k = 0; k < 5; k++)
        #pragma unroll
        for (int j = 0; j < 4; j++)
            wreg[k][j] = act ? W1[k * HID + f0 + j] : 0.0f;

    if (d >= N) return;

    float dd = dis[d];
    float sw = dd * dd;                    // self-loop norm
    const float* xr = x + (size_t)d * 5;
    float t0 = sw * xr[0], t1 = sw * xr[1], t2 = sw * xr[2], t3 = sw * xr[3], t4 = sw * xr[4];
    float m[4];
    #pragma unroll
    for (int j = 0; j < 4; j++)
        m[j] = t0*wreg[0][j] + t1*wreg[1][j] + t2*wreg[2][j] + t3*wreg[3][j] + t4*wreg[4][j];

    unsigned p0 = off[d], p1 = off[d + 1];
    unsigned p = p0;
    for (; p + 4 <= p1; p += 4){
        int2 e0 = sedge[p], e1 = sedge[p+1], e2 = sedge[p+2], e3 = sedge[p+3];
        const float* s0 = x + (size_t)e0.x * 5;
        const float* s1 = x + (size_t)e1.x * 5;
        const float* s2 = x + (size_t)e2.x * 5;
        const float* s3 = x + (size_t)e3.x * 5;
        float a0[5], a1[5], a2[5], a3[5];
        #pragma unroll
        for (int k = 0; k < 5; k++){ a0[k]=s0[k]; a1[k]=s1[k]; a2[k]=s2[k]; a3[k]=s3[k]; }
        float w0 = __int_as_float(e0.y), w1 = __int_as_float(e1.y);
        float w2 = __int_as_float(e2.y), w3 = __int_as_float(e3.y);
        #pragma unroll
        for (int k = 0; k < 5; k++){ a0[k]*=w0; a1[k]*=w1; a2[k]*=w2; a3[k]*=w3; }
        #pragma unroll
        for (int j = 0; j < 4; j++){
            float v0 = a0[0]*wreg[0][j]+a0[1]*wreg[1][j]+a0[2]*wreg[2][j]+a0[3]*wreg[3][j]+a0[4]*wreg[4][j];
            float v1 = a1[0]*wreg[0][j]+a1[1]*wreg[1][j]+a1[2]*wreg[2][j]+a1[3]*wreg[3][j]+a1[4]*wreg[4][j];
            float v2 = a2[0]*wreg[0][j]+a2[1]*wreg[1][j]+a2[2]*wreg[2][j]+a2[3]*wreg[3][j]+a2[4]*wreg[4][j];
            float v3 = a3[0]*wreg[0][j]+a3[1]*wreg[1][j]+a3[2]*wreg[2][j]+a3[3]*wreg[3][j]+a3[4]*wreg[4][j];
            m[j] = fmaxf(m[j], fmaxf(fmaxf(v0, v1), fmaxf(v2, v3)));
        }
    }
    for (; p < p1; p++){
        int2 e0 = sedge[p];
        const float* s0 = x + (size_t)e0.x * 5;
        float w0 = __int_as_float(e0.y);
        float a0[5];
        #pragma unroll
        for (int k = 0; k < 5; k++) a0[k] = w0 * s0[k];
        #pragma unroll
        for (int j = 0; j < 4; j++){
            float v0 = a0[0]*wreg[0][j]+a0[1]*wreg[1][j]+a0[2]*wreg[2][j]+a0[3]*wreg[3][j]+a0[4]*wreg[4][j];
            m[j] = fmaxf(m[j], v0);
        }
    }
    if (act){
        float4 b = *(const float4*)(bias + f0);
        float4 o;
        o.x = fmaxf(m[0] + b.x, 0.0f);
        o.y = fmaxf(m[1] + b.y, 0.0f);
        o.z = fmaxf(m[2] + b.z, 0.0f);
        o.w = fmaxf(m[3] + b.w, 0.0f);
        *(float4*)(out + (size_t)d * HID + f0) = o;
    }
}

// ---------------- optimized fp32 GEMM: C = A(MxK) @ W(KxNcol) [+bias] ----------------
// BM=64, BN=64, BK=16; 256 threads as 16x16, each 4x4 accs.
// float4 LDS reads both operands (2 ds_read_b128 per 16 FMA -> VALU-bound).
__global__ __launch_bounds__(256) void k_gemm32(const float* __restrict__ A,
                                                const float* __restrict__ W,
                                                const float* __restrict__ bias,
                                                float* __restrict__ C,
                                                int M, int K, int Ncol){
    __shared__ float sA[16][68];   // [k][m], stride 68 floats (272 B, 16B-aligned rows)
    __shared__ float sB[16][68];   // [k][n]
    int t  = threadIdx.x;
    int m0 = blockIdx.x * 64;
    int n0 = blockIdx.y * 64;
    int tx = t & 15;               // col group: cols tx*4 .. tx*4+3
    int ty = t >> 4;               // row group: rows ty*4 .. ty*4+3
    int row_a = t >> 2;            // 0..63
    int ka    = (t & 3) * 4;       // 0,4,8,12
    int rb    = t >> 4;            // 0..15
    int cb    = (t & 15) * 4;      // 0..60

    float acc[4][4];
    #pragma unroll
    for (int i = 0; i < 4; i++)
        #pragma unroll
        for (int j = 0; j < 4; j++) acc[i][j] = 0.0f;

    for (int k0 = 0; k0 < K; k0 += 16){
        float4 av = make_float4(0.f, 0.f, 0.f, 0.f);
        if (m0 + row_a < M)
            av = *(const float4*)(A + (size_t)(m0 + row_a) * K + k0 + ka);
        sA[ka + 0][row_a] = av.x;
        sA[ka + 1][row_a] = av.y;
        sA[ka + 2][row_a] = av.z;
        sA[ka + 3][row_a] = av.w;
        float4 bv = make_float4(0.f, 0.f, 0.f, 0.f);
        int n = n0 + cb;
        if (n + 3 < Ncol){
            bv = *(const float4*)(W + (size_t)(k0 + rb) * Ncol + n);
        } else if (n < Ncol){
            const float* wr = W + (size_t)(k0 + rb) * Ncol;
            bv.x = wr[n];
            if (n + 1 < Ncol) bv.y = wr[n + 1];
            if (n + 2 < Ncol) bv.z = wr[n + 2];
        }
        *(float4*)&sB[rb][cb] = bv;
        __syncthreads();
        #pragma unroll
        for (int k = 0; k < 16; k++){
            float4 a = *(const float4*)&sA[k][ty * 4];
            float4 b = *(const float4*)&sB[k][tx * 4];
            acc[0][0] += a.x*b.x; acc[0][1] += a.x*b.y; acc[0][2] += a.x*b.z; acc[0][3] += a.x*b.w;
            acc[1][0] += a.y*b.x; acc[1][1] += a.y*b.y; acc[1][2] += a.y*b.z; acc[1][3] += a.y*b.w;
            acc[2][0] += a.z*b.x; acc[2][1] += a.z*b.y; acc[2][2] += a.z*b.z; acc[2][3] += a.z*b.w;
            acc[3][0] += a.w*b.x; acc[3][1] += a.w*b.y; acc[3][2] += a.w*b.z; acc[3][3] += a.w*b.w;
        }
        __syncthreads();
    }
    #pragma unroll
    for (int i = 0; i < 4; i++){
        int m = m0 + ty * 4 + i;
        if (m >= M) continue;
        int n = n0 + tx * 4;
        float4 v = make_float4(acc[i][0], acc[i][1], acc[i][2], acc[i][3]);
        if (bias){
            v.x += bias[n]; 
            if (n + 1 < Ncol) v.y += bias[n + 1];
            if (n + 2 < Ncol) v.z += bias[n + 2];
            if (n + 3 < Ncol) v.w += bias[n + 3];
        }
        if (n + 3 < Ncol){
            *(float4*)(C + (size_t)m * Ncol + n) = v;
        } else if (n < Ncol){
            float* cr = C + (size_t)m * Ncol;
            cr[n] = v.x;
            if (n + 1 < Ncol) cr[n + 1] = v.y;
            if (n + 2 < Ncol) cr[n + 2] = v.z;
        }
    }
}

// ---------------- scatter-max aggregation + bias + ReLU (wave per destination) ----------------
// Full 960 B row gathers, unroll x4 for MLP.
__global__ __launch_bounds__(256) void k_agg(const float* __restrict__ H,
                                             const float* __restrict__ dis,
                                             const unsigned* __restrict__ off,
                                             const int2* __restrict__ sedge,
                                             const float* __restrict__ bias,
                                             float* __restrict__ out, int N){
    int d    = blockIdx.x * 4 + (threadIdx.x >> 6);
    int lane = threadIdx.x & 63;
    if (d >= N) return;
    bool act = lane < 60;   // 60 float4 = 240 floats

    float dd = dis[d];
    float sw = dd * dd;     // self-loop norm
    float4 m = make_float4(-FLT_MAX, -FLT_MAX, -FLT_MAX, -FLT_MAX);
    if (act){
        float4 h = ((const float4*)(H + (size_t)d * HID))[lane];
        m.x = sw * h.x; m.y = sw * h.y; m.z = sw * h.z; m.w = sw * h.w;
    }
    unsigned p0 = off[d], p1 = off[d + 1];
    unsigned p = p0;
    for (; p + 4 <= p1; p += 4){
        int2 e0 = sedge[p], e1 = sedge[p+1], e2 = sedge[p+2], e3 = sedge[p+3];
        if (act){
            float w0 = __int_as_float(e0.y), w1 = __int_as_float(e1.y);
            float w2 = __int_as_float(e2.y), w3 = __int_as_float(e3.y);
            float4 g0 = ((const float4*)(H + (size_t)e0.x * HID))[lane];
            float4 g1 = ((const float4*)(H + (size_t)e1.x * HID))[lane];
            float4 g2 = ((const float4*)(H + (size_t)e2.x * HID))[lane];
            float4 g3 = ((const float4*)(H + (size_t)e3.x * HID))[lane];
            m.x = fmaxf(fmaxf(m.x, w0 * g0.x), fmaxf(w1 * g1.x, fmaxf(w2 * g2.x, w3 * g3.x)));
            m.y = fmaxf(fmaxf(m.y, w0 * g0.y), fmaxf(w1 * g1.y, fmaxf(w2 * g2.y, w3 * g3.y)));
            m.z = fmaxf(fmaxf(m.z, w0 * g0.z), fmaxf(w1 * g1.z, fmaxf(w2 * g2.z, w3 * g3.z)));
            m.w = fmaxf(fmaxf(m.w, w0 * g0.w), fmaxf(w1 * g1.w, fmaxf(w2 * g2.w, w3 * g3.w)));
        }
    }
    for (; p < p1; p++){
        int2 e0 = sedge[p];
        if (act){
            float w0 = __int_as_float(e0.y);
            float4 g0 = ((const float4*)(H + (size_t)e0.x * HID))[lane];
            m.x = fmaxf(m.x, w0 * g0.x); m.y = fmaxf(m.y, w0 * g0.y);
            m.z = fmaxf(m.z, w0 * g0.z); m.w = fmaxf(m.w, w0 * g0.w);
        }
    }
    if (act){
        float4 b = ((const float4*)bias)[lane];
        float4 o;
        o.x = fmaxf(m.x + b.x, 0.0f);
        o.y = fmaxf(m.y + b.y, 0.0f);
        o.z = fmaxf(m.z + b.z, 0.0f);
        o.w = fmaxf(m.w + b.w, 0.0f);
        ((float4*)(out + (size_t)d * HID))[lane] = o;
    }
}

extern "C" void kernel_launch(void* const* d_in, const int* in_sizes, int n_in,
                              void* d_out, int out_size, void* d_ws, size_t ws_size,
                              hipStream_t stream){
    const float* x  = (const float*)d_in[0];
    const int*   ei = (const int*)  d_in[1];
    const float* ew = (const float*)d_in[2];
    const float* W1 = (const float*)d_in[3];
    const float* b1 = (const float*)d_in[4];
    const float* W2 = (const float*)d_in[5];
    const float* b2 = (const float*)d_in[6];
    const float* We = (const float*)d_in[7];
    const float* be = (const float*)d_in[8];
    float* out = (float*)d_out;

    const int N = in_sizes[0] / 5;
    const int E = in_sizes[2];
    const int* row = ei;       // sources
    const int* col = ei + E;   // destinations

    char* w = (char*)d_ws;
    size_t o = 0;
    auto alloc = [&](size_t bytes) -> void* {
        void* p = w + o;
        o = alignUp(o + bytes, 256);
        return p;
    };
    float*    dis   = (float*)   alloc((size_t)N * 4);
    unsigned* cnt   = (unsigned*)alloc((size_t)N * 4);
    unsigned* off   = (unsigned*)alloc((size_t)(N + 1) * 4);
    unsigned* cur   = (unsigned*)alloc((size_t)N * 4);
    int2*     sedge = (int2*)    alloc((size_t)E * 8);
    float*    bufA  = (float*)   alloc((size_t)N * HID * 4);   // 48 MB
    float*    bufB  = (float*)   alloc((size_t)N * HID * 4);   // 48 MB
    (void)ws_size; (void)n_in; (void)out_size;

    int bn = (N + 255) / 256;
    int be_ = (E + 255) / 256;

    // graph build (shared by both conv layers)
    k_init    <<<bn, 256, 0, stream>>>(dis, cnt, N);
    k_deg_hist<<<be_, 256, 0, stream>>>(col, ew, dis, cnt, E);
    k_dis     <<<bn, 256, 0, stream>>>(dis, N);
    k_scan    <<<1, 1024, 0, stream>>>(cnt, off, cur, N);
    k_scatter <<<be_, 256, 0, stream>>>(row, col, ew, dis, cur, sedge, E);

    // layer 1: fused rank-5 linear + max-agg + b1 + ReLU
    k_agg1<<<(N + 3) / 4, 256, 0, stream>>>(x, W1, dis, off, sedge, b1, bufB, N);

    // layer 2: optimized fp32 GEMM, then full-row max-agg + b2 + ReLU
    dim3 g2((N + 63) / 64, (HID + 63) / 64);
    k_gemm32<<<g2, 256, 0, stream>>>(bufB, W2, nullptr, bufA, N, HID, HID);
    k_agg<<<(N + 3) / 4, 256, 0, stream>>>(bufA, dis, off, sedge, b2, bufB, N);

    // readout: out = h @ We + be
    dim3 g3((N + 63) / 64, (80 + 63) / 64);
    k_gemm32<<<g3, 256, 0, stream>>>(bufB, We, be, out, N, HID, 80);
}

// Round 4
// 870.640 us; speedup vs baseline: 1.1405x; 1.0073x over previous
//
#include <hip/hip_runtime.h>
#include <cfloat>

#define HID 240

static inline size_t alignUp(size_t x, size_t a){ return (x + a - 1) / a * a; }

// ---------------- init: deg=1 (self-loop weight), cnt=0 ----------------
__global__ void k_init(float* __restrict__ deg, unsigned* __restrict__ cnt, int N){
    int i = blockIdx.x * blockDim.x + threadIdx.x;
    if (i < N){ deg[i] = 1.0f; cnt[i] = 0u; }
}

// ---------------- degree sum + histogram by destination ----------------
__global__ void k_deg_hist(const int* __restrict__ col, const float* __restrict__ ew,
                           float* __restrict__ deg, unsigned* __restrict__ cnt, int E){
    int e = blockIdx.x * blockDim.x + threadIdx.x;
    if (e < E){
        int c = col[e];
        atomicAdd(&deg[c], ew[e]);
        atomicAdd(&cnt[c], 1u);
    }
}

// ---------------- dis = rsqrt(deg) ----------------
__global__ void k_dis(float* __restrict__ deg, int N){
    int i = blockIdx.x * blockDim.x + threadIdx.x;
    if (i < N) deg[i] = rsqrtf(deg[i]);
}

// ---------------- pad x[N][5] -> xp[N][8] (aligned float4 pairs) ----------------
__global__ void k_prep_x(const float* __restrict__ x, float* __restrict__ xp, int N){
    __shared__ float s[1280];
    int t = threadIdx.x;
    int rbase = blockIdx.x * 256;
    #pragma unroll
    for (int c = 0; c < 5; c++){
        int idx = rbase * 5 + t + 256 * c;
        s[t + 256 * c] = (idx < N * 5) ? x[idx] : 0.0f;
    }
    __syncthreads();
    #pragma unroll
    for (int c = 0; c < 8; c++){
        int pos = t + 256 * c;          // 0..2047 within block
        int r = pos >> 3, j = pos & 7;
        int grow = rbase + r;
        if (grow < N)
            xp[(size_t)grow * 8 + j] = (j < 5) ? s[r * 5 + j] : 0.0f;
    }
}

// ---------------- single-block exclusive scan over N bins ----------------
__global__ void k_scan(const unsigned* __restrict__ cnt, unsigned* __restrict__ off,
                       unsigned* __restrict__ cur, int N){
    __shared__ unsigned wsum[16];
    __shared__ unsigned carry;
    int t = threadIdx.x;
    int lane = t & 63, w = t >> 6;
    if (t == 0) carry = 0u;
    __syncthreads();
    for (int base = 0; base < N; base += 1024){
        int i = base + t;
        unsigned v = (i < N) ? cnt[i] : 0u;
        unsigned x = v;
        #pragma unroll
        for (int o = 1; o < 64; o <<= 1){
            unsigned u = __shfl_up(x, (unsigned)o, 64);
            if (lane >= o) x += u;
        }
        if (lane == 63) wsum[w] = x;
        __syncthreads();
        if (t < 16){
            unsigned y = wsum[t];
            #pragma unroll
            for (int o = 1; o < 16; o <<= 1){
                unsigned u = __shfl_up(y, (unsigned)o, 16);
                if (t >= o) y += u;
            }
            wsum[t] = y;
        }
        __syncthreads();
        unsigned wbase = (w > 0) ? wsum[w - 1] : 0u;
        unsigned excl = carry + wbase + x - v;
        if (i < N){ off[i] = excl; cur[i] = excl; }
        __syncthreads();
        if (t == 0) carry += wsum[15];
        __syncthreads();
    }
    if (t == 0) off[N] = carry;
}

// ---------------- scatter edges into CSR-by-destination ----------------
__global__ void k_scatter(const int* __restrict__ row, const int* __restrict__ col,
                          const float* __restrict__ ew, const float* __restrict__ dis,
                          unsigned* __restrict__ cur, int2* __restrict__ sedge, int E){
    int e = blockIdx.x * blockDim.x + threadIdx.x;
    if (e < E){
        int r = row[e], c = col[e];
        float nw = dis[r] * ew[e] * dis[c];
        unsigned p = atomicAdd(&cur[c], 1u);
        sedge[p] = make_int2(r, __float_as_int(nw));
    }
}

// ---------------- fused layer-1: max-agg of norm*(x[src]@W1), +b1, ReLU ----------------
// xp rows are 32 B aligned: 2 vector loads per edge instead of 5 scalar.
__global__ __launch_bounds__(256) void k_agg1(const float* __restrict__ xp,
                                              const float* __restrict__ W1,
                                              const float* __restrict__ dis,
                                              const unsigned* __restrict__ off,
                                              const int2* __restrict__ sedge,
                                              const float* __restrict__ bias,
                                              float* __restrict__ out, int N){
    int d    = blockIdx.x * 4 + (threadIdx.x >> 6);
    int lane = threadIdx.x & 63;
    bool act = lane < 60;
    int f0 = lane * 4;

    float wreg[5][4];
    #pragma unroll
    for (int k = 0; k < 5; k++)
        #pragma unroll
        for (int j = 0; j < 4; j++)
            wreg[k][j] = act ? W1[k * HID + f0 + j] : 0.0f;

    if (d >= N) return;

    const float4* xp4 = (const float4*)xp;   // row r = xp4[2r], xp4[2r+1]

    float dd = dis[d];
    float sw = dd * dd;
    float4 dl = xp4[2 * (size_t)d];
    float4 dh = xp4[2 * (size_t)d + 1];
    float t0 = sw * dl.x, t1 = sw * dl.y, t2 = sw * dl.z, t3 = sw * dl.w, t4 = sw * dh.x;
    float m[4];
    #pragma unroll
    for (int j = 0; j < 4; j++)
        m[j] = t0*wreg[0][j] + t1*wreg[1][j] + t2*wreg[2][j] + t3*wreg[3][j] + t4*wreg[4][j];

    unsigned p0 = off[d], p1 = off[d + 1];
    unsigned p = p0;
    for (; p + 4 <= p1; p += 4){
        int2 e0 = sedge[p], e1 = sedge[p+1], e2 = sedge[p+2], e3 = sedge[p+3];
        float4 l0 = xp4[2*(size_t)e0.x], h0 = xp4[2*(size_t)e0.x + 1];
        float4 l1 = xp4[2*(size_t)e1.x], h1 = xp4[2*(size_t)e1.x + 1];
        float4 l2 = xp4[2*(size_t)e2.x], h2 = xp4[2*(size_t)e2.x + 1];
        float4 l3 = xp4[2*(size_t)e3.x], h3 = xp4[2*(size_t)e3.x + 1];
        float w0 = __int_as_float(e0.y), w1 = __int_as_float(e1.y);
        float w2 = __int_as_float(e2.y), w3 = __int_as_float(e3.y);
        float a0[5] = {w0*l0.x, w0*l0.y, w0*l0.z, w0*l0.w, w0*h0.x};
        float a1[5] = {w1*l1.x, w1*l1.y, w1*l1.z, w1*l1.w, w1*h1.x};
        float a2[5] = {w2*l2.x, w2*l2.y, w2*l2.z, w2*l2.w, w2*h2.x};
        float a3[5] = {w3*l3.x, w3*l3.y, w3*l3.z, w3*l3.w, w3*h3.x};
        #pragma unroll
        for (int j = 0; j < 4; j++){
            float v0 = a0[0]*wreg[0][j]+a0[1]*wreg[1][j]+a0[2]*wreg[2][j]+a0[3]*wreg[3][j]+a0[4]*wreg[4][j];
            float v1 = a1[0]*wreg[0][j]+a1[1]*wreg[1][j]+a1[2]*wreg[2][j]+a1[3]*wreg[3][j]+a1[4]*wreg[4][j];
            float v2 = a2[0]*wreg[0][j]+a2[1]*wreg[1][j]+a2[2]*wreg[2][j]+a2[3]*wreg[3][j]+a2[4]*wreg[4][j];
            float v3 = a3[0]*wreg[0][j]+a3[1]*wreg[1][j]+a3[2]*wreg[2][j]+a3[3]*wreg[3][j]+a3[4]*wreg[4][j];
            m[j] = fmaxf(m[j], fmaxf(fmaxf(v0, v1), fmaxf(v2, v3)));
        }
    }
    for (; p < p1; p++){
        int2 e0 = sedge[p];
        float4 l0 = xp4[2*(size_t)e0.x], h0 = xp4[2*(size_t)e0.x + 1];
        float w0 = __int_as_float(e0.y);
        float a0[5] = {w0*l0.x, w0*l0.y, w0*l0.z, w0*l0.w, w0*h0.x};
        #pragma unroll
        for (int j = 0; j < 4; j++){
            float v0 = a0[0]*wreg[0][j]+a0[1]*wreg[1][j]+a0[2]*wreg[2][j]+a0[3]*wreg[3][j]+a0[4]*wreg[4][j];
            m[j] = fmaxf(m[j], v0);
        }
    }
    if (act){
        float4 b = *(const float4*)(bias + f0);
        float4 o;
        o.x = fmaxf(m[0] + b.x, 0.0f);
        o.y = fmaxf(m[1] + b.y, 0.0f);
        o.z = fmaxf(m[2] + b.z, 0.0f);
        o.w = fmaxf(m[3] + b.w, 0.0f);
        *(float4*)(out + (size_t)d * HID + f0) = o;
    }
}

// ---------------- fp32 GEMM: C = A(MxK) @ W(KxNcol) [+bias] ----------------
// TRANSPOSED GRID: blockIdx.x = n-tile (fast) so consecutive blocks share the
// A tile via L2 (A fetched ~once from HBM). Register prefetch of next tile.
__global__ __launch_bounds__(256) void k_gemm32(const float* __restrict__ A,
                                                const float* __restrict__ W,
                                                const float* __restrict__ bias,
                                                float* __restrict__ C,
                                                int M, int K, int Ncol){
    __shared__ float sA[16][68];
    __shared__ float sB[16][68];
    int t  = threadIdx.x;
    int n0 = blockIdx.x * 64;     // n fast
    int m0 = blockIdx.y * 64;
    int tx = t & 15;
    int ty = t >> 4;
    int row_a = t >> 2;
    int ka    = (t & 3) * 4;
    int rb    = t >> 4;
    int cb    = (t & 15) * 4;

    float acc[4][4];
    #pragma unroll
    for (int i = 0; i < 4; i++)
        #pragma unroll
        for (int j = 0; j < 4; j++) acc[i][j] = 0.0f;

    auto loadA = [&](int k0) -> float4 {
        float4 av = make_float4(0.f, 0.f, 0.f, 0.f);
        if (m0 + row_a < M)
            av = *(const float4*)(A + (size_t)(m0 + row_a) * K + k0 + ka);
        return av;
    };
    auto loadB = [&](int k0) -> float4 {
        float4 bv = make_float4(0.f, 0.f, 0.f, 0.f);
        int n = n0 + cb;
        if (n + 3 < Ncol){
            bv = *(const float4*)(W + (size_t)(k0 + rb) * Ncol + n);
        } else if (n < Ncol){
            const float* wr = W + (size_t)(k0 + rb) * Ncol;
            bv.x = wr[n];
            if (n + 1 < Ncol) bv.y = wr[n + 1];
            if (n + 2 < Ncol) bv.z = wr[n + 2];
        }
        return bv;
    };

    float4 av = loadA(0);
    float4 bv = loadB(0);

    for (int k0 = 0; k0 < K; k0 += 16){
        sA[ka + 0][row_a] = av.x;
        sA[ka + 1][row_a] = av.y;
        sA[ka + 2][row_a] = av.z;
        sA[ka + 3][row_a] = av.w;
        *(float4*)&sB[rb][cb] = bv;
        __syncthreads();
        if (k0 + 16 < K){           // prefetch next tile during compute
            av = loadA(k0 + 16);
            bv = loadB(k0 + 16);
        }
        #pragma unroll
        for (int k = 0; k < 16; k++){
            float4 a = *(const float4*)&sA[k][ty * 4];
            float4 b = *(const float4*)&sB[k][tx * 4];
            acc[0][0] += a.x*b.x; acc[0][1] += a.x*b.y; acc[0][2] += a.x*b.z; acc[0][3] += a.x*b.w;
            acc[1][0] += a.y*b.x; acc[1][1] += a.y*b.y; acc[1][2] += a.y*b.z; acc[1][3] += a.y*b.w;
            acc[2][0] += a.z*b.x; acc[2][1] += a.z*b.y; acc[2][2] += a.z*b.z; acc[2][3] += a.z*b.w;
            acc[3][0] += a.w*b.x; acc[3][1] += a.w*b.y; acc[3][2] += a.w*b.z; acc[3][3] += a.w*b.w;
        }
        __syncthreads();
    }
    #pragma unroll
    for (int i = 0; i < 4; i++){
        int m = m0 + ty * 4 + i;
        if (m >= M) continue;
        int n = n0 + tx * 4;
        float4 v = make_float4(acc[i][0], acc[i][1], acc[i][2], acc[i][3]);
        if (bias){
            v.x += bias[n];
            if (n + 1 < Ncol) v.y += bias[n + 1];
            if (n + 2 < Ncol) v.z += bias[n + 2];
            if (n + 3 < Ncol) v.w += bias[n + 3];
        }
        if (n + 3 < Ncol){
            *(float4*)(C + (size_t)m * Ncol + n) = v;
        } else if (n < Ncol){
            float* cr = C + (size_t)m * Ncol;
            cr[n] = v.x;
            if (n + 1 < Ncol) cr[n + 1] = v.y;
            if (n + 2 < Ncol) cr[n + 2] = v.z;
        }
    }
}

// ---------------- scatter-max aggregation + bias + ReLU (wave per destination) ----------------
// Full 960 B row gathers, unroll x8 for more loads in flight.
__global__ __launch_bounds__(256) void k_agg(const float* __restrict__ H,
                                             const float* __restrict__ dis,
                                             const unsigned* __restrict__ off,
                                             const int2* __restrict__ sedge,
                                             const float* __restrict__ bias,
                                             float* __restrict__ out, int N){
    int d    = blockIdx.x * 4 + (threadIdx.x >> 6);
    int lane = threadIdx.x & 63;
    if (d >= N) return;
    bool act = lane < 60;

    float dd = dis[d];
    float sw = dd * dd;
    float4 m = make_float4(-FLT_MAX, -FLT_MAX, -FLT_MAX, -FLT_MAX);
    if (act){
        float4 h = ((const float4*)(H + (size_t)d * HID))[lane];
        m.x = sw * h.x; m.y = sw * h.y; m.z = sw * h.z; m.w = sw * h.w;
    }
    unsigned p0 = off[d], p1 = off[d + 1];
    unsigned p = p0;
    for (; p + 8 <= p1; p += 8){
        int2 e[8];
        #pragma unroll
        for (int u = 0; u < 8; u++) e[u] = sedge[p + u];
        if (act){
            float4 g[8];
            #pragma unroll
            for (int u = 0; u < 8; u++)
                g[u] = ((const float4*)(H + (size_t)e[u].x * HID))[lane];
            #pragma unroll
            for (int u = 0; u < 8; u++){
                float wu = __int_as_float(e[u].y);
                m.x = fmaxf(m.x, wu * g[u].x);
                m.y = fmaxf(m.y, wu * g[u].y);
                m.z = fmaxf(m.z, wu * g[u].z);
                m.w = fmaxf(m.w, wu * g[u].w);
            }
        }
    }
    for (; p < p1; p++){
        int2 e0 = sedge[p];
        if (act){
            float w0 = __int_as_float(e0.y);
            float4 g0 = ((const float4*)(H + (size_t)e0.x * HID))[lane];
            m.x = fmaxf(m.x, w0 * g0.x); m.y = fmaxf(m.y, w0 * g0.y);
            m.z = fmaxf(m.z, w0 * g0.z); m.w = fmaxf(m.w, w0 * g0.w);
        }
    }
    if (act){
        float4 b = ((const float4*)bias)[lane];
        float4 o;
        o.x = fmaxf(m.x + b.x, 0.0f);
        o.y = fmaxf(m.y + b.y, 0.0f);
        o.z = fmaxf(m.z + b.z, 0.0f);
        o.w = fmaxf(m.w + b.w, 0.0f);
        ((float4*)(out + (size_t)d * HID))[lane] = o;
    }
}

extern "C" void kernel_launch(void* const* d_in, const int* in_sizes, int n_in,
                              void* d_out, int out_size, void* d_ws, size_t ws_size,
                              hipStream_t stream){
    const float* x  = (const float*)d_in[0];
    const int*   ei = (const int*)  d_in[1];
    const float* ew = (const float*)d_in[2];
    const float* W1 = (const float*)d_in[3];
    const float* b1 = (const float*)d_in[4];
    const float* W2 = (const float*)d_in[5];
    const float* b2 = (const float*)d_in[6];
    const float* We = (const float*)d_in[7];
    const float* be = (const float*)d_in[8];
    float* out = (float*)d_out;

    const int N = in_sizes[0] / 5;
    const int E = in_sizes[2];
    const int* row = ei;
    const int* col = ei + E;

    char* w = (char*)d_ws;
    size_t o = 0;
    auto alloc = [&](size_t bytes) -> void* {
        void* p = w + o;
        o = alignUp(o + bytes, 256);
        return p;
    };
    float*    dis   = (float*)   alloc((size_t)N * 4);
    unsigned* cnt   = (unsigned*)alloc((size_t)N * 4);
    unsigned* off   = (unsigned*)alloc((size_t)(N + 1) * 4);
    unsigned* cur   = (unsigned*)alloc((size_t)N * 4);
    int2*     sedge = (int2*)    alloc((size_t)E * 8);
    float*    xp    = (float*)   alloc((size_t)N * 8 * 4);     // 1.6 MB
    float*    bufA  = (float*)   alloc((size_t)N * HID * 4);   // 48 MB
    float*    bufB  = (float*)   alloc((size_t)N * HID * 4);   // 48 MB
    (void)ws_size; (void)n_in; (void)out_size;

    int bn = (N + 255) / 256;
    int be_ = (E + 255) / 256;

    // graph build
    k_init    <<<bn, 256, 0, stream>>>(dis, cnt, N);
    k_deg_hist<<<be_, 256, 0, stream>>>(col, ew, dis, cnt, E);
    k_dis     <<<bn, 256, 0, stream>>>(dis, N);
    k_scan    <<<1, 1024, 0, stream>>>(cnt, off, cur, N);
    k_scatter <<<be_, 256, 0, stream>>>(row, col, ew, dis, cur, sedge, E);
    k_prep_x  <<<bn, 256, 0, stream>>>(x, xp, N);

    // layer 1: fused rank-5 linear + max-agg + b1 + ReLU
    k_agg1<<<(N + 3) / 4, 256, 0, stream>>>(xp, W1, dis, off, sedge, b1, bufB, N);

    // layer 2: GEMM (transposed grid), then full-row max-agg + b2 + ReLU
    dim3 g2((HID + 63) / 64, (N + 63) / 64);
    k_gemm32<<<g2, 256, 0, stream>>>(bufB, W2, nullptr, bufA, N, HID, HID);
    k_agg<<<(N + 3) / 4, 256, 0, stream>>>(bufA, dis, off, sedge, b2, bufB, N);

    // readout
    dim3 g3((80 + 63) / 64, (N + 63) / 64);
    k_gemm32<<<g3, 256, 0, stream>>>(bufB, We, be, out, N, HID, 80);
}

// Round 5
// 755.298 us; speedup vs baseline: 1.3147x; 1.1527x over previous
//
#include <hip/hip_runtime.h>
#include <cfloat>

#define HID 240

static inline size_t alignUp(size_t x, size_t a){ return (x + a - 1) / a * a; }

__device__ __forceinline__ float b2f(unsigned short u){
    return __uint_as_float(((unsigned)u) << 16);
}
__device__ __forceinline__ unsigned short f2b_rne(float f){
    unsigned r = __float_as_uint(f);
    r += 0x7FFFu + ((r >> 16) & 1u);
    return (unsigned short)(r >> 16);
}

// ---------------- init: deg=1 (self-loop weight), cnt=0 ----------------
__global__ void k_init(float* __restrict__ deg, unsigned* __restrict__ cnt, int N){
    int i = blockIdx.x * blockDim.x + threadIdx.x;
    if (i < N){ deg[i] = 1.0f; cnt[i] = 0u; }
}

// ---------------- degree sum + histogram by destination ----------------
__global__ void k_deg_hist(const int* __restrict__ col, const float* __restrict__ ew,
                           float* __restrict__ deg, unsigned* __restrict__ cnt, int E){
    int e = blockIdx.x * blockDim.x + threadIdx.x;
    if (e < E){
        int c = col[e];
        atomicAdd(&deg[c], ew[e]);
        atomicAdd(&cnt[c], 1u);
    }
}

// ---------------- dis = rsqrt(deg) ----------------
__global__ void k_dis(float* __restrict__ deg, int N){
    int i = blockIdx.x * blockDim.x + threadIdx.x;
    if (i < N) deg[i] = rsqrtf(deg[i]);
}

// ---------------- pad x[N][5] -> xp[N][8] ----------------
__global__ void k_prep_x(const float* __restrict__ x, float* __restrict__ xp, int N){
    __shared__ float s[1280];
    int t = threadIdx.x;
    int rbase = blockIdx.x * 256;
    #pragma unroll
    for (int c = 0; c < 5; c++){
        int idx = rbase * 5 + t + 256 * c;
        s[t + 256 * c] = (idx < N * 5) ? x[idx] : 0.0f;
    }
    __syncthreads();
    #pragma unroll
    for (int c = 0; c < 8; c++){
        int pos = t + 256 * c;
        int r = pos >> 3, j = pos & 7;
        int grow = rbase + r;
        if (grow < N)
            xp[(size_t)grow * 8 + j] = (j < 5) ? s[r * 5 + j] : 0.0f;
    }
}

// ---------------- multi-block scan: per-block sums ----------------
__global__ void k_bsum(const unsigned* __restrict__ cnt, unsigned* __restrict__ bsum, int N){
    int b = blockIdx.x;
    int i = b * 256 + threadIdx.x;
    unsigned v = (i < N) ? cnt[i] : 0u;
    #pragma unroll
    for (int o = 32; o > 0; o >>= 1) v += __shfl_down(v, (unsigned)o, 64);
    __shared__ unsigned ws[4];
    int lane = threadIdx.x & 63, w = threadIdx.x >> 6;
    if (lane == 0) ws[w] = v;
    __syncthreads();
    if (threadIdx.x == 0) bsum[b] = ws[0] + ws[1] + ws[2] + ws[3];
}

// ---------------- scan of block sums (nb <= 256), single tiny block ----------------
__global__ void k_bscan(const unsigned* __restrict__ bsum, unsigned* __restrict__ boff, int nb){
    __shared__ unsigned s[256];
    int t = threadIdx.x;
    unsigned v = (t < nb) ? bsum[t] : 0u;
    s[t] = v;
    __syncthreads();
    for (int o = 1; o < 256; o <<= 1){
        unsigned u = (t >= o) ? s[t - o] : 0u;
        __syncthreads();
        s[t] += u;
        __syncthreads();
    }
    if (t < nb) boff[t] = s[t] - v;   // exclusive
}

// ---------------- final offsets: off[i] = boff[b] + intra-block exclusive ----------------
__global__ void k_offs(const unsigned* __restrict__ cnt, const unsigned* __restrict__ boff,
                       unsigned* __restrict__ off, unsigned* __restrict__ cur,
                       int N, unsigned Etot){
    int b = blockIdx.x, t = threadIdx.x;
    int i = b * 256 + t;
    unsigned v = (i < N) ? cnt[i] : 0u;
    int lane = t & 63, w = t >> 6;
    unsigned x = v;
    #pragma unroll
    for (int o = 1; o < 64; o <<= 1){
        unsigned u = __shfl_up(x, (unsigned)o, 64);
        if (lane >= o) x += u;
    }
    __shared__ unsigned ws[4];
    if (lane == 63) ws[w] = x;
    __syncthreads();
    unsigned wb = 0;
    if (w > 0) wb += ws[0];
    if (w > 1) wb += ws[1];
    if (w > 2) wb += ws[2];
    unsigned excl = boff[b] + wb + x - v;
    if (i < N){ off[i] = excl; cur[i] = excl; }
    if (b == 0 && t == 0) off[N] = Etot;
}

// ---------------- scatter edges into CSR-by-destination ----------------
__global__ void k_scatter(const int* __restrict__ row, const int* __restrict__ col,
                          const float* __restrict__ ew, const float* __restrict__ dis,
                          unsigned* __restrict__ cur, int2* __restrict__ sedge, int E){
    int e = blockIdx.x * blockDim.x + threadIdx.x;
    if (e < E){
        int r = row[e], c = col[e];
        float nw = dis[r] * ew[e] * dis[c];
        unsigned p = atomicAdd(&cur[c], 1u);
        sedge[p] = make_int2(r, __float_as_int(nw));
    }
}

// ---------------- fused layer-1: max-agg of norm*(x[src]@W1), +b1, ReLU ----------------
__global__ __launch_bounds__(256) void k_agg1(const float* __restrict__ xp,
                                              const float* __restrict__ W1,
                                              const float* __restrict__ dis,
                                              const unsigned* __restrict__ off,
                                              const int2* __restrict__ sedge,
                                              const float* __restrict__ bias,
                                              float* __restrict__ out, int N){
    int d    = blockIdx.x * 4 + (threadIdx.x >> 6);
    int lane = threadIdx.x & 63;
    bool act = lane < 60;
    int f0 = lane * 4;

    float wreg[5][4];
    #pragma unroll
    for (int k = 0; k < 5; k++)
        #pragma unroll
        for (int j = 0; j < 4; j++)
            wreg[k][j] = act ? W1[k * HID + f0 + j] : 0.0f;

    if (d >= N) return;

    const float4* xp4 = (const float4*)xp;

    float dd = dis[d];
    float sw = dd * dd;
    float4 dl = xp4[2 * (size_t)d];
    float4 dh = xp4[2 * (size_t)d + 1];
    float t0 = sw * dl.x, t1 = sw * dl.y, t2 = sw * dl.z, t3 = sw * dl.w, t4 = sw * dh.x;
    float m[4];
    #pragma unroll
    for (int j = 0; j < 4; j++)
        m[j] = t0*wreg[0][j] + t1*wreg[1][j] + t2*wreg[2][j] + t3*wreg[3][j] + t4*wreg[4][j];

    unsigned p0 = off[d], p1 = off[d + 1];
    unsigned p = p0;
    for (; p + 4 <= p1; p += 4){
        int2 e0 = sedge[p], e1 = sedge[p+1], e2 = sedge[p+2], e3 = sedge[p+3];
        float4 l0 = xp4[2*(size_t)e0.x], h0 = xp4[2*(size_t)e0.x + 1];
        float4 l1 = xp4[2*(size_t)e1.x], h1 = xp4[2*(size_t)e1.x + 1];
        float4 l2 = xp4[2*(size_t)e2.x], h2 = xp4[2*(size_t)e2.x + 1];
        float4 l3 = xp4[2*(size_t)e3.x], h3 = xp4[2*(size_t)e3.x + 1];
        float w0 = __int_as_float(e0.y), w1 = __int_as_float(e1.y);
        float w2 = __int_as_float(e2.y), w3 = __int_as_float(e3.y);
        float a0[5] = {w0*l0.x, w0*l0.y, w0*l0.z, w0*l0.w, w0*h0.x};
        float a1[5] = {w1*l1.x, w1*l1.y, w1*l1.z, w1*l1.w, w1*h1.x};
        float a2[5] = {w2*l2.x, w2*l2.y, w2*l2.z, w2*l2.w, w2*h2.x};
        float a3[5] = {w3*l3.x, w3*l3.y, w3*l3.z, w3*l3.w, w3*h3.x};
        #pragma unroll
        for (int j = 0; j < 4; j++){
            float v0 = a0[0]*wreg[0][j]+a0[1]*wreg[1][j]+a0[2]*wreg[2][j]+a0[3]*wreg[3][j]+a0[4]*wreg[4][j];
            float v1 = a1[0]*wreg[0][j]+a1[1]*wreg[1][j]+a1[2]*wreg[2][j]+a1[3]*wreg[3][j]+a1[4]*wreg[4][j];
            float v2 = a2[0]*wreg[0][j]+a2[1]*wreg[1][j]+a2[2]*wreg[2][j]+a2[3]*wreg[3][j]+a2[4]*wreg[4][j];
            float v3 = a3[0]*wreg[0][j]+a3[1]*wreg[1][j]+a3[2]*wreg[2][j]+a3[3]*wreg[3][j]+a3[4]*wreg[4][j];
            m[j] = fmaxf(m[j], fmaxf(fmaxf(v0, v1), fmaxf(v2, v3)));
        }
    }
    for (; p < p1; p++){
        int2 e0 = sedge[p];
        float4 l0 = xp4[2*(size_t)e0.x], h0 = xp4[2*(size_t)e0.x + 1];
        float w0 = __int_as_float(e0.y);
        float a0[5] = {w0*l0.x, w0*l0.y, w0*l0.z, w0*l0.w, w0*h0.x};
        #pragma unroll
        for (int j = 0; j < 4; j++){
            float v0 = a0[0]*wreg[0][j]+a0[1]*wreg[1][j]+a0[2]*wreg[2][j]+a0[3]*wreg[3][j]+a0[4]*wreg[4][j];
            m[j] = fmaxf(m[j], v0);
        }
    }
    if (act){
        float4 b = *(const float4*)(bias + f0);
        float4 o;
        o.x = fmaxf(m[0] + b.x, 0.0f);
        o.y = fmaxf(m[1] + b.y, 0.0f);
        o.z = fmaxf(m[2] + b.z, 0.0f);
        o.w = fmaxf(m[3] + b.w, 0.0f);
        *(float4*)(out + (size_t)d * HID + f0) = o;
    }
}

// ---------------- fp32 GEMM: C = A(MxK) @ W(KxNcol) [+bias fp32 path only] ----------------
// OB16: emit bf16 (RNE) rows for the gather phase. Grid: blockIdx.x = n (fast).
template <bool OB16>
__global__ __launch_bounds__(256) void k_gemm32(const float* __restrict__ A,
                                                const float* __restrict__ W,
                                                const float* __restrict__ bias,
                                                void* __restrict__ Cv,
                                                int M, int K, int Ncol){
    __shared__ float sA[16][68];
    __shared__ float sB[16][68];
    int t  = threadIdx.x;
    int n0 = blockIdx.x * 64;
    int m0 = blockIdx.y * 64;
    int tx = t & 15;
    int ty = t >> 4;
    int row_a = t >> 2;
    int ka    = (t & 3) * 4;
    int rb    = t >> 4;
    int cb    = (t & 15) * 4;

    float acc[4][4];
    #pragma unroll
    for (int i = 0; i < 4; i++)
        #pragma unroll
        for (int j = 0; j < 4; j++) acc[i][j] = 0.0f;

    auto loadA = [&](int k0) -> float4 {
        float4 av = make_float4(0.f, 0.f, 0.f, 0.f);
        if (m0 + row_a < M)
            av = *(const float4*)(A + (size_t)(m0 + row_a) * K + k0 + ka);
        return av;
    };
    auto loadB = [&](int k0) -> float4 {
        float4 bv = make_float4(0.f, 0.f, 0.f, 0.f);
        int n = n0 + cb;
        if (n + 3 < Ncol){
            bv = *(const float4*)(W + (size_t)(k0 + rb) * Ncol + n);
        } else if (n < Ncol){
            const float* wr = W + (size_t)(k0 + rb) * Ncol;
            bv.x = wr[n];
            if (n + 1 < Ncol) bv.y = wr[n + 1];
            if (n + 2 < Ncol) bv.z = wr[n + 2];
        }
        return bv;
    };

    float4 av = loadA(0);
    float4 bv = loadB(0);

    for (int k0 = 0; k0 < K; k0 += 16){
        sA[ka + 0][row_a] = av.x;
        sA[ka + 1][row_a] = av.y;
        sA[ka + 2][row_a] = av.z;
        sA[ka + 3][row_a] = av.w;
        *(float4*)&sB[rb][cb] = bv;
        __syncthreads();
        if (k0 + 16 < K){
            av = loadA(k0 + 16);
            bv = loadB(k0 + 16);
        }
        #pragma unroll
        for (int k = 0; k < 16; k++){
            float4 a = *(const float4*)&sA[k][ty * 4];
            float4 b = *(const float4*)&sB[k][tx * 4];
            acc[0][0] += a.x*b.x; acc[0][1] += a.x*b.y; acc[0][2] += a.x*b.z; acc[0][3] += a.x*b.w;
            acc[1][0] += a.y*b.x; acc[1][1] += a.y*b.y; acc[1][2] += a.y*b.z; acc[1][3] += a.y*b.w;
            acc[2][0] += a.z*b.x; acc[2][1] += a.z*b.y; acc[2][2] += a.z*b.z; acc[2][3] += a.z*b.w;
            acc[3][0] += a.w*b.x; acc[3][1] += a.w*b.y; acc[3][2] += a.w*b.z; acc[3][3] += a.w*b.w;
        }
        __syncthreads();
    }
    #pragma unroll
    for (int i = 0; i < 4; i++){
        int m = m0 + ty * 4 + i;
        if (m >= M) continue;
        int n = n0 + tx * 4;
        float4 v = make_float4(acc[i][0], acc[i][1], acc[i][2], acc[i][3]);
        if (OB16){
            if (n + 3 < Ncol){
                ushort4 u;
                u.x = f2b_rne(v.x); u.y = f2b_rne(v.y);
                u.z = f2b_rne(v.z); u.w = f2b_rne(v.w);
                *(ushort4*)((unsigned short*)Cv + (size_t)m * Ncol + n) = u;
            }
        } else {
            float* C = (float*)Cv;
            if (bias){
                v.x += bias[n];
                if (n + 1 < Ncol) v.y += bias[n + 1];
                if (n + 2 < Ncol) v.z += bias[n + 2];
                if (n + 3 < Ncol) v.w += bias[n + 3];
            }
            if (n + 3 < Ncol){
                *(float4*)(C + (size_t)m * Ncol + n) = v;
            } else if (n < Ncol){
                float* cr = C + (size_t)m * Ncol;
                cr[n] = v.x;
                if (n + 1 < Ncol) cr[n + 1] = v.y;
                if (n + 2 < Ncol) cr[n + 2] = v.z;
            }
        }
    }
}

// ---------------- scatter-max aggregation over bf16 rows, +bias, ReLU ----------------
// 480 B row gathers (half the fill traffic of fp32). Unroll x4.
__global__ __launch_bounds__(256) void k_aggb(const unsigned short* __restrict__ H2,
                                              const float* __restrict__ dis,
                                              const unsigned* __restrict__ off,
                                              const int2* __restrict__ sedge,
                                              const float* __restrict__ bias,
                                              float* __restrict__ out, int N){
    int d    = blockIdx.x * 4 + (threadIdx.x >> 6);
    int lane = threadIdx.x & 63;
    if (d >= N) return;
    bool act = lane < 60;

    float dd = dis[d];
    float sw = dd * dd;
    float4 m = make_float4(-FLT_MAX, -FLT_MAX, -FLT_MAX, -FLT_MAX);
    if (act){
        ushort4 u = ((const ushort4*)(H2 + (size_t)d * HID))[lane];
        m.x = sw * b2f(u.x); m.y = sw * b2f(u.y);
        m.z = sw * b2f(u.z); m.w = sw * b2f(u.w);
    }
    unsigned p0 = off[d], p1 = off[d + 1];
    unsigned p = p0;
    for (; p + 4 <= p1; p += 4){
        int2 e0 = sedge[p], e1 = sedge[p+1], e2 = sedge[p+2], e3 = sedge[p+3];
        if (act){
            ushort4 g0 = ((const ushort4*)(H2 + (size_t)e0.x * HID))[lane];
            ushort4 g1 = ((const ushort4*)(H2 + (size_t)e1.x * HID))[lane];
            ushort4 g2 = ((const ushort4*)(H2 + (size_t)e2.x * HID))[lane];
            ushort4 g3 = ((const ushort4*)(H2 + (size_t)e3.x * HID))[lane];
            float w0 = __int_as_float(e0.y), w1 = __int_as_float(e1.y);
            float w2 = __int_as_float(e2.y), w3 = __int_as_float(e3.y);
            m.x = fmaxf(fmaxf(m.x, w0*b2f(g0.x)), fmaxf(w1*b2f(g1.x), fmaxf(w2*b2f(g2.x), w3*b2f(g3.x))));
            m.y = fmaxf(fmaxf(m.y, w0*b2f(g0.y)), fmaxf(w1*b2f(g1.y), fmaxf(w2*b2f(g2.y), w3*b2f(g3.y))));
            m.z = fmaxf(fmaxf(m.z, w0*b2f(g0.z)), fmaxf(w1*b2f(g1.z), fmaxf(w2*b2f(g2.z), w3*b2f(g3.z))));
            m.w = fmaxf(fmaxf(m.w, w0*b2f(g0.w)), fmaxf(w1*b2f(g1.w), fmaxf(w2*b2f(g2.w), w3*b2f(g3.w))));
        }
    }
    for (; p < p1; p++){
        int2 e0 = sedge[p];
        if (act){
            ushort4 g0 = ((const ushort4*)(H2 + (size_t)e0.x * HID))[lane];
            float w0 = __int_as_float(e0.y);
            m.x = fmaxf(m.x, w0 * b2f(g0.x)); m.y = fmaxf(m.y, w0 * b2f(g0.y));
            m.z = fmaxf(m.z, w0 * b2f(g0.z)); m.w = fmaxf(m.w, w0 * b2f(g0.w));
        }
    }
    if (act){
        float4 b = ((const float4*)bias)[lane];
        float4 o;
        o.x = fmaxf(m.x + b.x, 0.0f);
        o.y = fmaxf(m.y + b.y, 0.0f);
        o.z = fmaxf(m.z + b.z, 0.0f);
        o.w = fmaxf(m.w + b.w, 0.0f);
        ((float4*)(out + (size_t)d * HID))[lane] = o;
    }
}

extern "C" void kernel_launch(void* const* d_in, const int* in_sizes, int n_in,
                              void* d_out, int out_size, void* d_ws, size_t ws_size,
                              hipStream_t stream){
    const float* x  = (const float*)d_in[0];
    const int*   ei = (const int*)  d_in[1];
    const float* ew = (const float*)d_in[2];
    const float* W1 = (const float*)d_in[3];
    const float* b1 = (const float*)d_in[4];
    const float* W2 = (const float*)d_in[5];
    const float* b2 = (const float*)d_in[6];
    const float* We = (const float*)d_in[7];
    const float* be = (const float*)d_in[8];
    float* out = (float*)d_out;

    const int N = in_sizes[0] / 5;
    const int E = in_sizes[2];
    const int* row = ei;
    const int* col = ei + E;
    const int nb = (N + 255) / 256;

    char* w = (char*)d_ws;
    size_t o = 0;
    auto alloc = [&](size_t bytes) -> void* {
        void* p = w + o;
        o = alignUp(o + bytes, 256);
        return p;
    };
    float*          dis   = (float*)          alloc((size_t)N * 4);
    unsigned*       cnt   = (unsigned*)       alloc((size_t)N * 4);
    unsigned*       off   = (unsigned*)       alloc((size_t)(N + 1) * 4);
    unsigned*       cur   = (unsigned*)       alloc((size_t)N * 4);
    unsigned*       bsum  = (unsigned*)       alloc((size_t)nb * 4);
    unsigned*       boff  = (unsigned*)       alloc((size_t)nb * 4);
    int2*           sedge = (int2*)           alloc((size_t)E * 8);
    float*          xp    = (float*)          alloc((size_t)N * 8 * 4);
    unsigned short* bufH2 = (unsigned short*) alloc((size_t)N * HID * 2);  // 24 MB bf16
    float*          bufB  = (float*)          alloc((size_t)N * HID * 4);  // 48 MB
    (void)ws_size; (void)n_in; (void)out_size;

    int bn = nb;
    int be_ = (E + 255) / 256;

    // graph build
    k_init    <<<bn, 256, 0, stream>>>(dis, cnt, N);
    k_deg_hist<<<be_, 256, 0, stream>>>(col, ew, dis, cnt, E);
    k_dis     <<<bn, 256, 0, stream>>>(dis, N);
    k_bsum    <<<bn, 256, 0, stream>>>(cnt, bsum, N);
    k_bscan   <<<1, 256, 0, stream>>>(bsum, boff, nb);
    k_offs    <<<bn, 256, 0, stream>>>(cnt, boff, off, cur, N, (unsigned)E);
    k_scatter <<<be_, 256, 0, stream>>>(row, col, ew, dis, cur, sedge, E);
    k_prep_x  <<<bn, 256, 0, stream>>>(x, xp, N);

    // layer 1: fused rank-5 linear + max-agg + b1 + ReLU
    k_agg1<<<(N + 3) / 4, 256, 0, stream>>>(xp, W1, dis, off, sedge, b1, bufB, N);

    // layer 2: GEMM -> bf16 rows, then bf16-gather max-agg + b2 + ReLU
    dim3 g2((HID + 63) / 64, (N + 63) / 64);
    k_gemm32<true><<<g2, 256, 0, stream>>>(bufB, W2, nullptr, bufH2, N, HID, HID);
    k_aggb<<<(N + 3) / 4, 256, 0, stream>>>(bufH2, dis, off, sedge, b2, bufB, N);

    // readout
    dim3 g3((80 + 63) / 64, (N + 63) / 64);
    k_gemm32<false><<<g3, 256, 0, stream>>>(bufB, We, be, out, N, HID, 80);
}

// Round 6
// 718.293 us; speedup vs baseline: 1.3824x; 1.0515x over previous
//
#include <hip/hip_runtime.h>
#include <cfloat>

#define HID 240

static inline size_t alignUp(size_t x, size_t a){ return (x + a - 1) / a * a; }

typedef __bf16 bf16x8 __attribute__((ext_vector_type(8)));
typedef float  f32x16 __attribute__((ext_vector_type(16)));

__device__ __forceinline__ float b2f(unsigned short u){
    return __uint_as_float(((unsigned)u) << 16);
}
__device__ __forceinline__ unsigned short f2b_rne(float f){
    unsigned r = __float_as_uint(f);
    r += 0x7FFFu + ((r >> 16) & 1u);
    return (unsigned short)(r >> 16);
}

// ---------------- init: deg=1 (self-loop weight), cnt=0 ----------------
__global__ void k_init(float* __restrict__ deg, unsigned* __restrict__ cnt, int N){
    int i = blockIdx.x * blockDim.x + threadIdx.x;
    if (i < N){ deg[i] = 1.0f; cnt[i] = 0u; }
}

// ---------------- degree sum + histogram by destination ----------------
__global__ void k_deg_hist(const int* __restrict__ col, const float* __restrict__ ew,
                           float* __restrict__ deg, unsigned* __restrict__ cnt, int E){
    int e = blockIdx.x * blockDim.x + threadIdx.x;
    if (e < E){
        int c = col[e];
        atomicAdd(&deg[c], ew[e]);
        atomicAdd(&cnt[c], 1u);
    }
}

// ---------------- dis = rsqrt(deg) ----------------
__global__ void k_dis(float* __restrict__ deg, int N){
    int i = blockIdx.x * blockDim.x + threadIdx.x;
    if (i < N) deg[i] = rsqrtf(deg[i]);
}

// ---------------- pad x[N][5] -> xp[N][8] ----------------
__global__ void k_prep_x(const float* __restrict__ x, float* __restrict__ xp, int N){
    __shared__ float s[1280];
    int t = threadIdx.x;
    int rbase = blockIdx.x * 256;
    #pragma unroll
    for (int c = 0; c < 5; c++){
        int idx = rbase * 5 + t + 256 * c;
        s[t + 256 * c] = (idx < N * 5) ? x[idx] : 0.0f;
    }
    __syncthreads();
    #pragma unroll
    for (int c = 0; c < 8; c++){
        int pos = t + 256 * c;
        int r = pos >> 3, j = pos & 7;
        int grow = rbase + r;
        if (grow < N)
            xp[(size_t)grow * 8 + j] = (j < 5) ? s[r * 5 + j] : 0.0f;
    }
}

// ---------------- split W[K][Ncol] into transposed bf16 hi/lo planes Bt[n][K] ----------------
__global__ void k_prep_w(const float* __restrict__ W, unsigned short* __restrict__ Bth,
                         unsigned short* __restrict__ Btl, int Kd, int Ncol, int Npad){
    int i = blockIdx.x * 256 + threadIdx.x;
    if (i < Npad * Kd){
        int n = i / Kd, k = i - n * Kd;
        float v = (n < Ncol) ? W[(size_t)k * Ncol + n] : 0.0f;
        unsigned short hi = f2b_rne(v);
        float lo = v - b2f(hi);
        Bth[i] = hi;
        Btl[i] = f2b_rne(lo);
    }
}

// ---------------- multi-block scan: per-block sums ----------------
__global__ void k_bsum(const unsigned* __restrict__ cnt, unsigned* __restrict__ bsum, int N){
    int b = blockIdx.x;
    int i = b * 256 + threadIdx.x;
    unsigned v = (i < N) ? cnt[i] : 0u;
    #pragma unroll
    for (int o = 32; o > 0; o >>= 1) v += __shfl_down(v, (unsigned)o, 64);
    __shared__ unsigned ws[4];
    int lane = threadIdx.x & 63, w = threadIdx.x >> 6;
    if (lane == 0) ws[w] = v;
    __syncthreads();
    if (threadIdx.x == 0) bsum[b] = ws[0] + ws[1] + ws[2] + ws[3];
}

// ---------------- scan of block sums (nb <= 256) ----------------
__global__ void k_bscan(const unsigned* __restrict__ bsum, unsigned* __restrict__ boff, int nb){
    __shared__ unsigned s[256];
    int t = threadIdx.x;
    unsigned v = (t < nb) ? bsum[t] : 0u;
    s[t] = v;
    __syncthreads();
    for (int o = 1; o < 256; o <<= 1){
        unsigned u = (t >= o) ? s[t - o] : 0u;
        __syncthreads();
        s[t] += u;
        __syncthreads();
    }
    if (t < nb) boff[t] = s[t] - v;
}

// ---------------- final offsets ----------------
__global__ void k_offs(const unsigned* __restrict__ cnt, const unsigned* __restrict__ boff,
                       unsigned* __restrict__ off, unsigned* __restrict__ cur,
                       int N, unsigned Etot){
    int b = blockIdx.x, t = threadIdx.x;
    int i = b * 256 + t;
    unsigned v = (i < N) ? cnt[i] : 0u;
    int lane = t & 63, w = t >> 6;
    unsigned x = v;
    #pragma unroll
    for (int o = 1; o < 64; o <<= 1){
        unsigned u = __shfl_up(x, (unsigned)o, 64);
        if (lane >= o) x += u;
    }
    __shared__ unsigned ws[4];
    if (lane == 63) ws[w] = x;
    __syncthreads();
    unsigned wb = 0;
    if (w > 0) wb += ws[0];
    if (w > 1) wb += ws[1];
    if (w > 2) wb += ws[2];
    unsigned excl = boff[b] + wb + x - v;
    if (i < N){ off[i] = excl; cur[i] = excl; }
    if (b == 0 && t == 0) off[N] = Etot;
}

// ---------------- scatter edges into CSR-by-destination ----------------
__global__ void k_scatter(const int* __restrict__ row, const int* __restrict__ col,
                          const float* __restrict__ ew, const float* __restrict__ dis,
                          unsigned* __restrict__ cur, int2* __restrict__ sedge, int E){
    int e = blockIdx.x * blockDim.x + threadIdx.x;
    if (e < E){
        int r = row[e], c = col[e];
        float nw = dis[r] * ew[e] * dis[c];
        unsigned p = atomicAdd(&cur[c], 1u);
        sedge[p] = make_int2(r, __float_as_int(nw));
    }
}

// ---------------- fused layer-1: max-agg of norm*(x[src]@W1), +b1, ReLU ----------------
__global__ __launch_bounds__(256) void k_agg1(const float* __restrict__ xp,
                                              const float* __restrict__ W1,
                                              const float* __restrict__ dis,
                                              const unsigned* __restrict__ off,
                                              const int2* __restrict__ sedge,
                                              const float* __restrict__ bias,
                                              float* __restrict__ out, int N){
    int d    = blockIdx.x * 4 + (threadIdx.x >> 6);
    int lane = threadIdx.x & 63;
    bool act = lane < 60;
    int f0 = lane * 4;

    float wreg[5][4];
    #pragma unroll
    for (int k = 0; k < 5; k++)
        #pragma unroll
        for (int j = 0; j < 4; j++)
            wreg[k][j] = act ? W1[k * HID + f0 + j] : 0.0f;

    if (d >= N) return;

    const float4* xp4 = (const float4*)xp;

    float dd = dis[d];
    float sw = dd * dd;
    float4 dl = xp4[2 * (size_t)d];
    float4 dh = xp4[2 * (size_t)d + 1];
    float t0 = sw * dl.x, t1 = sw * dl.y, t2 = sw * dl.z, t3 = sw * dl.w, t4 = sw * dh.x;
    float m[4];
    #pragma unroll
    for (int j = 0; j < 4; j++)
        m[j] = t0*wreg[0][j] + t1*wreg[1][j] + t2*wreg[2][j] + t3*wreg[3][j] + t4*wreg[4][j];

    unsigned p0 = off[d], p1 = off[d + 1];
    unsigned p = p0;
    for (; p + 4 <= p1; p += 4){
        int2 e0 = sedge[p], e1 = sedge[p+1], e2 = sedge[p+2], e3 = sedge[p+3];
        float4 l0 = xp4[2*(size_t)e0.x], h0 = xp4[2*(size_t)e0.x + 1];
        float4 l1 = xp4[2*(size_t)e1.x], h1 = xp4[2*(size_t)e1.x + 1];
        float4 l2 = xp4[2*(size_t)e2.x], h2 = xp4[2*(size_t)e2.x + 1];
        float4 l3 = xp4[2*(size_t)e3.x], h3 = xp4[2*(size_t)e3.x + 1];
        float w0 = __int_as_float(e0.y), w1 = __int_as_float(e1.y);
        float w2 = __int_as_float(e2.y), w3 = __int_as_float(e3.y);
        float a0[5] = {w0*l0.x, w0*l0.y, w0*l0.z, w0*l0.w, w0*h0.x};
        float a1[5] = {w1*l1.x, w1*l1.y, w1*l1.z, w1*l1.w, w1*h1.x};
        float a2[5] = {w2*l2.x, w2*l2.y, w2*l2.z, w2*l2.w, w2*h2.x};
        float a3[5] = {w3*l3.x, w3*l3.y, w3*l3.z, w3*l3.w, w3*h3.x};
        #pragma unroll
        for (int j = 0; j < 4; j++){
            float v0 = a0[0]*wreg[0][j]+a0[1]*wreg[1][j]+a0[2]*wreg[2][j]+a0[3]*wreg[3][j]+a0[4]*wreg[4][j];
            float v1 = a1[0]*wreg[0][j]+a1[1]*wreg[1][j]+a1[2]*wreg[2][j]+a1[3]*wreg[3][j]+a1[4]*wreg[4][j];
            float v2 = a2[0]*wreg[0][j]+a2[1]*wreg[1][j]+a2[2]*wreg[2][j]+a2[3]*wreg[3][j]+a2[4]*wreg[4][j];
            float v3 = a3[0]*wreg[0][j]+a3[1]*wreg[1][j]+a3[2]*wreg[2][j]+a3[3]*wreg[3][j]+a3[4]*wreg[4][j];
            m[j] = fmaxf(m[j], fmaxf(fmaxf(v0, v1), fmaxf(v2, v3)));
        }
    }
    for (; p < p1; p++){
        int2 e0 = sedge[p];
        float4 l0 = xp4[2*(size_t)e0.x], h0 = xp4[2*(size_t)e0.x + 1];
        float w0 = __int_as_float(e0.y);
        float a0[5] = {w0*l0.x, w0*l0.y, w0*l0.z, w0*l0.w, w0*h0.x};
        #pragma unroll
        for (int j = 0; j < 4; j++){
            float v0 = a0[0]*wreg[0][j]+a0[1]*wreg[1][j]+a0[2]*wreg[2][j]+a0[3]*wreg[3][j]+a0[4]*wreg[4][j];
            m[j] = fmaxf(m[j], v0);
        }
    }
    if (act){
        float4 b = *(const float4*)(bias + f0);
        float4 o;
        o.x = fmaxf(m[0] + b.x, 0.0f);
        o.y = fmaxf(m[1] + b.y, 0.0f);
        o.z = fmaxf(m[2] + b.z, 0.0f);
        o.w = fmaxf(m[3] + b.w, 0.0f);
        *(float4*)(out + (size_t)d * HID + f0) = o;
    }
}

// ---------------- split-bf16 MFMA GEMM: C = A(M x 240) @ W(240 x Ncol) ----------------
// A fp32, split hi/lo in LDS per K16-step. B pre-split bf16 planes Bt[n][K] read
// directly from global (L2-resident). A=Ah+Al, B=Bh+Bl; compute AhBh+AhBl+AlBh
// (AlBl ~ 2^-17 rel, dropped) -> fp32-class accuracy.
// Block: 32m x 256n, 4 waves; wave w covers n [64w, 64w+64) as two 32x32 MFMA tiles.
template <bool OB16>
__global__ __launch_bounds__(256) void k_gemm_mfma(const float* __restrict__ A,
                                                   const unsigned short* __restrict__ Bth,
                                                   const unsigned short* __restrict__ Btl,
                                                   const float* __restrict__ bias,
                                                   void* __restrict__ Cv,
                                                   int M, int Ncol, int Npad){
    __shared__ unsigned short As_hi[32][24];   // [m][k], row 48 B (16B-aligned)
    __shared__ unsigned short As_lo[32][24];
    const int K = 240;
    int t = threadIdx.x;
    int wave = t >> 6, lane = t & 63;
    int m0 = blockIdx.x * 32;
    int n0 = wave * 64;
    bool wact = n0 < Npad;

    int lm   = lane & 31;
    int quad = lane >> 5;     // 0/1 -> k-half of 8

    f32x16 acc0 = {};
    f32x16 acc1 = {};

    for (int k0 = 0; k0 < K; k0 += 16){
        if (t < 128){
            int m = t >> 2, kq = (t & 3) * 4;
            float4 av = make_float4(0.f, 0.f, 0.f, 0.f);
            if (m0 + m < M) av = *(const float4*)(A + (size_t)(m0 + m) * K + k0 + kq);
            ushort4 hi, lo;
            hi.x = f2b_rne(av.x); lo.x = f2b_rne(av.x - b2f(hi.x));
            hi.y = f2b_rne(av.y); lo.y = f2b_rne(av.y - b2f(hi.y));
            hi.z = f2b_rne(av.z); lo.z = f2b_rne(av.z - b2f(hi.z));
            hi.w = f2b_rne(av.w); lo.w = f2b_rne(av.w - b2f(hi.w));
            *(ushort4*)&As_hi[m][kq] = hi;
            *(ushort4*)&As_lo[m][kq] = lo;
        }
        __syncthreads();
        if (wact){
            bf16x8 ah = *(const bf16x8*)&As_hi[lm][quad * 8];
            bf16x8 al = *(const bf16x8*)&As_lo[lm][quad * 8];
            size_t bo0 = (size_t)(n0 + lm) * K + k0 + quad * 8;
            size_t bo1 = (size_t)(n0 + 32 + lm) * K + k0 + quad * 8;
            bf16x8 bh0 = *(const bf16x8*)(Bth + bo0);
            bf16x8 bl0 = *(const bf16x8*)(Btl + bo0);
            bf16x8 bh1 = *(const bf16x8*)(Bth + bo1);
            bf16x8 bl1 = *(const bf16x8*)(Btl + bo1);
            acc0 = __builtin_amdgcn_mfma_f32_32x32x16_bf16(ah, bh0, acc0, 0, 0, 0);
            acc0 = __builtin_amdgcn_mfma_f32_32x32x16_bf16(ah, bl0, acc0, 0, 0, 0);
            acc0 = __builtin_amdgcn_mfma_f32_32x32x16_bf16(al, bh0, acc0, 0, 0, 0);
            acc1 = __builtin_amdgcn_mfma_f32_32x32x16_bf16(ah, bh1, acc1, 0, 0, 0);
            acc1 = __builtin_amdgcn_mfma_f32_32x32x16_bf16(ah, bl1, acc1, 0, 0, 0);
            acc1 = __builtin_amdgcn_mfma_f32_32x32x16_bf16(al, bh1, acc1, 0, 0, 0);
        }
        __syncthreads();
    }

    if (!wact) return;
    #pragma unroll
    for (int h = 0; h < 2; h++){
        int n = n0 + 32 * h + lm;
        if (n >= Ncol) continue;
        float bv = (!OB16 && bias) ? bias[n] : 0.0f;
        #pragma unroll
        for (int r = 0; r < 16; r++){
            int m = m0 + (r & 3) + 8 * (r >> 2) + 4 * quad;
            if (m >= M) continue;
            float v = (h == 0) ? acc0[r] : acc1[r];
            if (OB16){
                ((unsigned short*)Cv)[(size_t)m * Ncol + n] = f2b_rne(v);
            } else {
                ((float*)Cv)[(size_t)m * Ncol + n] = v + bv;
            }
        }
    }
}

// ---------------- scatter-max aggregation over bf16 rows, +bias, ReLU ----------------
__global__ __launch_bounds__(256) void k_aggb(const unsigned short* __restrict__ H2,
                                              const float* __restrict__ dis,
                                              const unsigned* __restrict__ off,
                                              const int2* __restrict__ sedge,
                                              const float* __restrict__ bias,
                                              float* __restrict__ out, int N){
    int d    = blockIdx.x * 4 + (threadIdx.x >> 6);
    int lane = threadIdx.x & 63;
    if (d >= N) return;
    bool act = lane < 60;

    float dd = dis[d];
    float sw = dd * dd;
    float4 m = make_float4(-FLT_MAX, -FLT_MAX, -FLT_MAX, -FLT_MAX);
    if (act){
        ushort4 u = ((const ushort4*)(H2 + (size_t)d * HID))[lane];
        m.x = sw * b2f(u.x); m.y = sw * b2f(u.y);
        m.z = sw * b2f(u.z); m.w = sw * b2f(u.w);
    }
    unsigned p0 = off[d], p1 = off[d + 1];
    unsigned p = p0;
    for (; p + 4 <= p1; p += 4){
        int2 e0 = sedge[p], e1 = sedge[p+1], e2 = sedge[p+2], e3 = sedge[p+3];
        if (act){
            ushort4 g0 = ((const ushort4*)(H2 + (size_t)e0.x * HID))[lane];
            ushort4 g1 = ((const ushort4*)(H2 + (size_t)e1.x * HID))[lane];
            ushort4 g2 = ((const ushort4*)(H2 + (size_t)e2.x * HID))[lane];
            ushort4 g3 = ((const ushort4*)(H2 + (size_t)e3.x * HID))[lane];
            float w0 = __int_as_float(e0.y), w1 = __int_as_float(e1.y);
            float w2 = __int_as_float(e2.y), w3 = __int_as_float(e3.y);
            m.x = fmaxf(fmaxf(m.x, w0*b2f(g0.x)), fmaxf(w1*b2f(g1.x), fmaxf(w2*b2f(g2.x), w3*b2f(g3.x))));
            m.y = fmaxf(fmaxf(m.y, w0*b2f(g0.y)), fmaxf(w1*b2f(g1.y), fmaxf(w2*b2f(g2.y), w3*b2f(g3.y))));
            m.z = fmaxf(fmaxf(m.z, w0*b2f(g0.z)), fmaxf(w1*b2f(g1.z), fmaxf(w2*b2f(g2.z), w3*b2f(g3.z))));
            m.w = fmaxf(fmaxf(m.w, w0*b2f(g0.w)), fmaxf(w1*b2f(g1.w), fmaxf(w2*b2f(g2.w), w3*b2f(g3.w))));
        }
    }
    for (; p < p1; p++){
        int2 e0 = sedge[p];
        if (act){
            ushort4 g0 = ((const ushort4*)(H2 + (size_t)e0.x * HID))[lane];
            float w0 = __int_as_float(e0.y);
            m.x = fmaxf(m.x, w0 * b2f(g0.x)); m.y = fmaxf(m.y, w0 * b2f(g0.y));
            m.z = fmaxf(m.z, w0 * b2f(g0.z)); m.w = fmaxf(m.w, w0 * b2f(g0.w));
        }
    }
    if (act){
        float4 b = ((const float4*)bias)[lane];
        float4 o;
        o.x = fmaxf(m.x + b.x, 0.0f);
        o.y = fmaxf(m.y + b.y, 0.0f);
        o.z = fmaxf(m.z + b.z, 0.0f);
        o.w = fmaxf(m.w + b.w, 0.0f);
        ((float4*)(out + (size_t)d * HID))[lane] = o;
    }
}

extern "C" void kernel_launch(void* const* d_in, const int* in_sizes, int n_in,
                              void* d_out, int out_size, void* d_ws, size_t ws_size,
                              hipStream_t stream){
    const float* x  = (const float*)d_in[0];
    const int*   ei = (const int*)  d_in[1];
    const float* ew = (const float*)d_in[2];
    const float* W1 = (const float*)d_in[3];
    const float* b1 = (const float*)d_in[4];
    const float* W2 = (const float*)d_in[5];
    const float* b2 = (const float*)d_in[6];
    const float* We = (const float*)d_in[7];
    const float* be = (const float*)d_in[8];
    float* out = (float*)d_out;

    const int N = in_sizes[0] / 5;
    const int E = in_sizes[2];
    const int* row = ei;
    const int* col = ei + E;
    const int nb = (N + 255) / 256;

    char* w = (char*)d_ws;
    size_t o = 0;
    auto alloc = [&](size_t bytes) -> void* {
        void* p = w + o;
        o = alignUp(o + bytes, 256);
        return p;
    };
    float*          dis   = (float*)          alloc((size_t)N * 4);
    unsigned*       cnt   = (unsigned*)       alloc((size_t)N * 4);
    unsigned*       off   = (unsigned*)       alloc((size_t)(N + 1) * 4);
    unsigned*       cur   = (unsigned*)       alloc((size_t)N * 4);
    unsigned*       bsum  = (unsigned*)       alloc((size_t)nb * 4);
    unsigned*       boff  = (unsigned*)       alloc((size_t)nb * 4);
    int2*           sedge = (int2*)           alloc((size_t)E * 8);
    float*          xp    = (float*)          alloc((size_t)N * 8 * 4);
    unsigned short* Bt2h  = (unsigned short*) alloc((size_t)256 * HID * 2);
    unsigned short* Bt2l  = (unsigned short*) alloc((size_t)256 * HID * 2);
    unsigned short* Bt3h  = (unsigned short*) alloc((size_t)128 * HID * 2);
    unsigned short* Bt3l  = (unsigned short*) alloc((size_t)128 * HID * 2);
    unsigned short* bufH2 = (unsigned short*) alloc((size_t)N * HID * 2);  // 24 MB bf16
    float*          bufB  = (float*)          alloc((size_t)N * HID * 4);  // 48 MB
    (void)ws_size; (void)n_in; (void)out_size;

    int bn = nb;
    int be_ = (E + 255) / 256;

    // graph build + weight prep
    k_init    <<<bn, 256, 0, stream>>>(dis, cnt, N);
    k_deg_hist<<<be_, 256, 0, stream>>>(col, ew, dis, cnt, E);
    k_dis     <<<bn, 256, 0, stream>>>(dis, N);
    k_bsum    <<<bn, 256, 0, stream>>>(cnt, bsum, N);
    k_bscan   <<<1, 256, 0, stream>>>(bsum, boff, nb);
    k_offs    <<<bn, 256, 0, stream>>>(cnt, boff, off, cur, N, (unsigned)E);
    k_scatter <<<be_, 256, 0, stream>>>(row, col, ew, dis, cur, sedge, E);
    k_prep_x  <<<bn, 256, 0, stream>>>(x, xp, N);
    k_prep_w  <<<(256 * HID + 255) / 256, 256, 0, stream>>>(W2, Bt2h, Bt2l, HID, HID, 256);
    k_prep_w  <<<(128 * HID + 255) / 256, 256, 0, stream>>>(We, Bt3h, Bt3l, HID, 80, 128);

    // layer 1: fused rank-5 linear + max-agg + b1 + ReLU
    k_agg1<<<(N + 3) / 4, 256, 0, stream>>>(xp, W1, dis, off, sedge, b1, bufB, N);

    // layer 2: split-bf16 MFMA GEMM -> bf16 rows, then bf16-gather max-agg + b2 + ReLU
    int gm = (N + 31) / 32;
    k_gemm_mfma<true><<<gm, 256, 0, stream>>>(bufB, Bt2h, Bt2l, nullptr, bufH2, N, HID, 256);
    k_aggb<<<(N + 3) / 4, 256, 0, stream>>>(bufH2, dis, off, sedge, b2, bufB, N);

    // readout: split-bf16 MFMA GEMM -> fp32 out + be
    k_gemm_mfma<false><<<gm, 256, 0, stream>>>(bufB, Bt3h, Bt3l, be, out, N, 80, 128);
}

// Round 7
// 636.859 us; speedup vs baseline: 1.5592x; 1.1279x over previous
//
#include <hip/hip_runtime.h>
#include <cfloat>

#define HID 240

static inline size_t alignUp(size_t x, size_t a){ return (x + a - 1) / a * a; }

typedef __bf16 bf16x8 __attribute__((ext_vector_type(8)));
typedef unsigned short u16x8 __attribute__((ext_vector_type(8)));
typedef float  f32x16 __attribute__((ext_vector_type(16)));

__device__ __forceinline__ float b2f(unsigned short u){
    return __uint_as_float(((unsigned)u) << 16);
}
__device__ __forceinline__ unsigned short f2b_rne(float f){
    unsigned r = __float_as_uint(f);
    r += 0x7FFFu + ((r >> 16) & 1u);
    return (unsigned short)(r >> 16);
}

// ---------------- init: deg=1 (self-loop weight), cnt=0 ----------------
__global__ void k_init(float* __restrict__ deg, unsigned* __restrict__ cnt, int N){
    int i = blockIdx.x * blockDim.x + threadIdx.x;
    if (i < N){ deg[i] = 1.0f; cnt[i] = 0u; }
}

// ---------------- degree sum + histogram by destination ----------------
__global__ void k_deg_hist(const int* __restrict__ col, const float* __restrict__ ew,
                           float* __restrict__ deg, unsigned* __restrict__ cnt, int E){
    int e = blockIdx.x * blockDim.x + threadIdx.x;
    if (e < E){
        int c = col[e];
        atomicAdd(&deg[c], ew[e]);
        atomicAdd(&cnt[c], 1u);
    }
}

// ---------------- dis = rsqrt(deg) ----------------
__global__ void k_dis(float* __restrict__ deg, int N){
    int i = blockIdx.x * blockDim.x + threadIdx.x;
    if (i < N) deg[i] = rsqrtf(deg[i]);
}

// ---------------- pad x[N][5] -> xp[N][8] ----------------
__global__ void k_prep_x(const float* __restrict__ x, float* __restrict__ xp, int N){
    __shared__ float s[1280];
    int t = threadIdx.x;
    int rbase = blockIdx.x * 256;
    #pragma unroll
    for (int c = 0; c < 5; c++){
        int idx = rbase * 5 + t + 256 * c;
        s[t + 256 * c] = (idx < N * 5) ? x[idx] : 0.0f;
    }
    __syncthreads();
    #pragma unroll
    for (int c = 0; c < 8; c++){
        int pos = t + 256 * c;
        int r = pos >> 3, j = pos & 7;
        int grow = rbase + r;
        if (grow < N)
            xp[(size_t)grow * 8 + j] = (j < 5) ? s[r * 5 + j] : 0.0f;
    }
}

// ---------------- W1 (5x240) -> per-lane MFMA B-fragments [s][tile][lane][8] bf16 ----------------
// B-frag layout (validated r6): lane holds B[k=(lane>>5)*8+i][n=32*tile+(lane&31)], i=0..7.
__global__ void k_prep_w1(const float* __restrict__ W1, unsigned short* __restrict__ W1f){
    int i = blockIdx.x * 256 + threadIdx.x;
    if (i < 2 * 8 * 64 * 8){
        int k    = i & 7;
        int lane = (i >> 3) & 63;
        int j    = (i >> 9) & 7;
        int s    = i >> 12;
        int lm = lane & 31, quad = lane >> 5;
        int kg = quad * 8 + k;
        int col = 32 * j + lm;
        float v = (kg < 5 && col < HID) ? W1[kg * HID + col] : 0.0f;
        unsigned short hi = f2b_rne(v);
        W1f[i] = (s == 0) ? hi : f2b_rne(v - b2f(hi));
    }
}

// ---------------- split W[K][Ncol] into transposed bf16 hi/lo planes Bt[n][K] ----------------
__global__ void k_prep_w(const float* __restrict__ W, unsigned short* __restrict__ Bth,
                         unsigned short* __restrict__ Btl, int Kd, int Ncol, int Npad){
    int i = blockIdx.x * 256 + threadIdx.x;
    if (i < Npad * Kd){
        int n = i / Kd, k = i - n * Kd;
        float v = (n < Ncol) ? W[(size_t)k * Ncol + n] : 0.0f;
        unsigned short hi = f2b_rne(v);
        float lo = v - b2f(hi);
        Bth[i] = hi;
        Btl[i] = f2b_rne(lo);
    }
}

// ---------------- padded-CSR scan: per-block sums of chunk counts ----------------
// chunks_d = ceil((cnt_d + 1) / 32)  (self-loop included)
__global__ void k_bsum(const unsigned* __restrict__ cnt, unsigned* __restrict__ bsum, int N){
    int b = blockIdx.x;
    int i = b * 256 + threadIdx.x;
    unsigned v = (i < N) ? ((cnt[i] + 32u) >> 5) : 0u;
    #pragma unroll
    for (int o = 32; o > 0; o >>= 1) v += __shfl_down(v, (unsigned)o, 64);
    __shared__ unsigned ws[4];
    int lane = threadIdx.x & 63, w = threadIdx.x >> 6;
    if (lane == 0) ws[w] = v;
    __syncthreads();
    if (threadIdx.x == 0) bsum[b] = ws[0] + ws[1] + ws[2] + ws[3];
}

// ---------------- scan of block sums (nb <= 256); also writes poff[N] ----------------
__global__ void k_bscan(const unsigned* __restrict__ bsum, unsigned* __restrict__ boff,
                        unsigned* __restrict__ poff, int nb, int N){
    __shared__ unsigned s[256];
    int t = threadIdx.x;
    unsigned v = (t < nb) ? bsum[t] : 0u;
    s[t] = v;
    __syncthreads();
    for (int o = 1; o < 256; o <<= 1){
        unsigned u = (t >= o) ? s[t - o] : 0u;
        __syncthreads();
        s[t] += u;
        __syncthreads();
    }
    if (t < nb) boff[t] = s[t] - v;
    if (t == 0) poff[N] = 32u * s[nb - 1];
}

// ---------------- final padded offsets; cur starts after the self slot ----------------
__global__ void k_offs(const unsigned* __restrict__ cnt, const unsigned* __restrict__ boff,
                       unsigned* __restrict__ poff, unsigned* __restrict__ cur, int N){
    int b = blockIdx.x, t = threadIdx.x;
    int i = b * 256 + t;
    unsigned v = (i < N) ? ((cnt[i] + 32u) >> 5) : 0u;
    int lane = t & 63, w = t >> 6;
    unsigned x = v;
    #pragma unroll
    for (int o = 1; o < 64; o <<= 1){
        unsigned u = __shfl_up(x, (unsigned)o, 64);
        if (lane >= o) x += u;
    }
    __shared__ unsigned ws[4];
    if (lane == 63) ws[w] = x;
    __syncthreads();
    unsigned wb = 0;
    if (w > 0) wb += ws[0];
    if (w > 1) wb += ws[1];
    if (w > 2) wb += ws[2];
    if (i < N){
        unsigned p = 32u * (boff[b] + wb + x - v);
        poff[i] = p;
        cur[i] = p + 1u;      // slot p holds the self-loop edge
    }
}

// ---------------- fill self-loop slot + tail padding with (d, dis^2) ----------------
__global__ void k_fill(const unsigned* __restrict__ cnt, const unsigned* __restrict__ poff,
                       const float* __restrict__ dis, int2* __restrict__ sedge, int N){
    int d = blockIdx.x * 256 + threadIdx.x;
    if (d < N){
        float dd = dis[d];
        int2 v = make_int2(d, __float_as_int(dd * dd));
        unsigned s0 = poff[d];
        unsigned s1 = poff[d + 1];
        sedge[s0] = v;
        for (unsigned s = s0 + 1u + cnt[d]; s < s1; s++) sedge[s] = v;
    }
}

// ---------------- scatter edges into padded CSR ----------------
__global__ void k_scatter(const int* __restrict__ row, const int* __restrict__ col,
                          const float* __restrict__ ew, const float* __restrict__ dis,
                          unsigned* __restrict__ cur, int2* __restrict__ sedge, int E){
    int e = blockIdx.x * blockDim.x + threadIdx.x;
    if (e < E){
        int r = row[e], c = col[e];
        float nw = dis[r] * ew[e] * dis[c];
        unsigned p = atomicAdd(&cur[c], 1u);
        sedge[p] = make_int2(r, __float_as_int(nw));
    }
}

// ---------------- layer-1 fused linear+max-agg via MFMA ----------------
// Per destination: padded edge chunks of 32 (self + dups). Lanes 0-31 gather
// w_e*x_e rows (K=16, 11 zero), split-bf16; 8 col-tiles x 3 MFMA; per-lane
// fmax over 16 acc rows -> column max (duplicate padding is idempotent).
// Each wave loops over dests (stride nwaves) to amortize W1-frag setup.
__global__ __launch_bounds__(256) void k_agg1m(const float* __restrict__ xp,
                                               const unsigned short* __restrict__ W1f,
                                               const unsigned* __restrict__ cnt,
                                               const unsigned* __restrict__ poff,
                                               const int2* __restrict__ sedge,
                                               const float* __restrict__ bias,
                                               float* __restrict__ out, int N, int nwaves){
    int wid  = blockIdx.x * 4 + (threadIdx.x >> 6);
    int lane = threadIdx.x & 63;
    int lm   = lane & 31;

    bf16x8 bh[8], bl[8];
    #pragma unroll
    for (int j = 0; j < 8; j++){
        bh[j] = *(const bf16x8*)(W1f + ((size_t)(0 * 8 + j) * 64 + lane) * 8);
        bl[j] = *(const bf16x8*)(W1f + ((size_t)(1 * 8 + j) * 64 + lane) * 8);
    }
    float bv[8];
    #pragma unroll
    for (int j = 0; j < 8; j++){
        int c = 32 * j + lm;
        bv[j] = (c < HID) ? bias[c] : 0.0f;
    }
    const f32x16 zv = {};

    for (int d = wid; d < N; d += nwaves){
        unsigned base = poff[d];
        unsigned nch  = (cnt[d] + 32u) >> 5;
        float m[8];
        #pragma unroll
        for (int j = 0; j < 8; j++) m[j] = -FLT_MAX;

        for (unsigned c = 0; c < nch; c++){
            u16x8 ahu = (u16x8)0, alu = (u16x8)0;
            if (lane < 32){
                int2 e = sedge[base + 32u * c + (unsigned)lm];
                float w = __int_as_float(e.y);
                const float4* xr = (const float4*)(xp + (size_t)e.x * 8);
                float4 x0 = xr[0], x1 = xr[1];
                float p[5] = {w * x0.x, w * x0.y, w * x0.z, w * x0.w, w * x1.x};
                #pragma unroll
                for (int k = 0; k < 5; k++){
                    unsigned short h = f2b_rne(p[k]);
                    ahu[k] = h;
                    alu[k] = f2b_rne(p[k] - b2f(h));
                }
            }
            bf16x8 ah = __builtin_bit_cast(bf16x8, ahu);
            bf16x8 al = __builtin_bit_cast(bf16x8, alu);
            #pragma unroll
            for (int j = 0; j < 8; j += 2){
                f32x16 a0 = __builtin_amdgcn_mfma_f32_32x32x16_bf16(ah, bh[j],     zv, 0, 0, 0);
                f32x16 a1 = __builtin_amdgcn_mfma_f32_32x32x16_bf16(ah, bh[j + 1], zv, 0, 0, 0);
                a0 = __builtin_amdgcn_mfma_f32_32x32x16_bf16(ah, bl[j],     a0, 0, 0, 0);
                a1 = __builtin_amdgcn_mfma_f32_32x32x16_bf16(ah, bl[j + 1], a1, 0, 0, 0);
                a0 = __builtin_amdgcn_mfma_f32_32x32x16_bf16(al, bh[j],     a0, 0, 0, 0);
                a1 = __builtin_amdgcn_mfma_f32_32x32x16_bf16(al, bh[j + 1], a1, 0, 0, 0);
                #pragma unroll
                for (int r = 0; r < 16; r++){
                    m[j]     = fmaxf(m[j],     a0[r]);
                    m[j + 1] = fmaxf(m[j + 1], a1[r]);
                }
            }
        }
        // combine the two row-halves (lane ^ 32), bias, ReLU, store
        float o[8];
        #pragma unroll
        for (int j = 0; j < 8; j++){
            float other = __shfl_xor(m[j], 32, 64);
            o[j] = fmaxf(fmaxf(m[j], other) + bv[j], 0.0f);
        }
        if (lane < 32){
            float* orow = out + (size_t)d * HID;
            #pragma unroll
            for (int j = 0; j < 8; j++){
                int c = 32 * j + lm;
                if (c < HID) orow[c] = o[j];
            }
        }
    }
}

// ---------------- split-bf16 MFMA GEMM: C = A(M x 240) @ W(240 x Ncol) ----------------
template <bool OB16>
__global__ __launch_bounds__(256) void k_gemm_mfma(const float* __restrict__ A,
                                                   const unsigned short* __restrict__ Bth,
                                                   const unsigned short* __restrict__ Btl,
                                                   const float* __restrict__ bias,
                                                   void* __restrict__ Cv,
                                                   int M, int Ncol, int Npad){
    __shared__ unsigned short As_hi[32][24];
    __shared__ unsigned short As_lo[32][24];
    const int K = 240;
    int t = threadIdx.x;
    int wave = t >> 6, lane = t & 63;
    int m0 = blockIdx.x * 32;
    int n0 = wave * 64;
    bool wact = n0 < Npad;

    int lm   = lane & 31;
    int quad = lane >> 5;

    f32x16 acc0 = {};
    f32x16 acc1 = {};

    for (int k0 = 0; k0 < K; k0 += 16){
        if (t < 128){
            int m = t >> 2, kq = (t & 3) * 4;
            float4 av = make_float4(0.f, 0.f, 0.f, 0.f);
            if (m0 + m < M) av = *(const float4*)(A + (size_t)(m0 + m) * K + k0 + kq);
            ushort4 hi, lo;
            hi.x = f2b_rne(av.x); lo.x = f2b_rne(av.x - b2f(hi.x));
            hi.y = f2b_rne(av.y); lo.y = f2b_rne(av.y - b2f(hi.y));
            hi.z = f2b_rne(av.z); lo.z = f2b_rne(av.z - b2f(hi.z));
            hi.w = f2b_rne(av.w); lo.w = f2b_rne(av.w - b2f(hi.w));
            *(ushort4*)&As_hi[m][kq] = hi;
            *(ushort4*)&As_lo[m][kq] = lo;
        }
        __syncthreads();
        if (wact){
            bf16x8 ah = *(const bf16x8*)&As_hi[lm][quad * 8];
            bf16x8 al = *(const bf16x8*)&As_lo[lm][quad * 8];
            size_t bo0 = (size_t)(n0 + lm) * K + k0 + quad * 8;
            size_t bo1 = (size_t)(n0 + 32 + lm) * K + k0 + quad * 8;
            bf16x8 bh0 = *(const bf16x8*)(Bth + bo0);
            bf16x8 bl0 = *(const bf16x8*)(Btl + bo0);
            bf16x8 bh1 = *(const bf16x8*)(Bth + bo1);
            bf16x8 bl1 = *(const bf16x8*)(Btl + bo1);
            acc0 = __builtin_amdgcn_mfma_f32_32x32x16_bf16(ah, bh0, acc0, 0, 0, 0);
            acc0 = __builtin_amdgcn_mfma_f32_32x32x16_bf16(ah, bl0, acc0, 0, 0, 0);
            acc0 = __builtin_amdgcn_mfma_f32_32x32x16_bf16(al, bh0, acc0, 0, 0, 0);
            acc1 = __builtin_amdgcn_mfma_f32_32x32x16_bf16(ah, bh1, acc1, 0, 0, 0);
            acc1 = __builtin_amdgcn_mfma_f32_32x32x16_bf16(ah, bl1, acc1, 0, 0, 0);
            acc1 = __builtin_amdgcn_mfma_f32_32x32x16_bf16(al, bh1, acc1, 0, 0, 0);
        }
        __syncthreads();
    }

    if (!wact) return;
    #pragma unroll
    for (int h = 0; h < 2; h++){
        int n = n0 + 32 * h + lm;
        if (n >= Ncol) continue;
        float bvv = (!OB16 && bias) ? bias[n] : 0.0f;
        #pragma unroll
        for (int r = 0; r < 16; r++){
            int m = m0 + (r & 3) + 8 * (r >> 2) + 4 * quad;
            if (m >= M) continue;
            float v = (h == 0) ? acc0[r] : acc1[r];
            if (OB16){
                ((unsigned short*)Cv)[(size_t)m * Ncol + n] = f2b_rne(v);
            } else {
                ((float*)Cv)[(size_t)m * Ncol + n] = v + bvv;
            }
        }
    }
}

// ---------------- layer-2 scatter-max over bf16 rows (self slot included), +bias, ReLU ----------------
__global__ __launch_bounds__(256) void k_aggb(const unsigned short* __restrict__ H2,
                                              const unsigned* __restrict__ cnt,
                                              const unsigned* __restrict__ poff,
                                              const int2* __restrict__ sedge,
                                              const float* __restrict__ bias,
                                              float* __restrict__ out, int N){
    int d    = blockIdx.x * 4 + (threadIdx.x >> 6);
    int lane = threadIdx.x & 63;
    if (d >= N) return;
    bool act = lane < 60;

    float4 m = make_float4(-FLT_MAX, -FLT_MAX, -FLT_MAX, -FLT_MAX);
    unsigned p0 = poff[d], p1 = p0 + 1u + cnt[d];
    unsigned p = p0;
    for (; p + 4 <= p1; p += 4){
        int2 e0 = sedge[p], e1 = sedge[p+1], e2 = sedge[p+2], e3 = sedge[p+3];
        if (act){
            ushort4 g0 = ((const ushort4*)(H2 + (size_t)e0.x * HID))[lane];
            ushort4 g1 = ((const ushort4*)(H2 + (size_t)e1.x * HID))[lane];
            ushort4 g2 = ((const ushort4*)(H2 + (size_t)e2.x * HID))[lane];
            ushort4 g3 = ((const ushort4*)(H2 + (size_t)e3.x * HID))[lane];
            float w0 = __int_as_float(e0.y), w1 = __int_as_float(e1.y);
            float w2 = __int_as_float(e2.y), w3 = __int_as_float(e3.y);
            m.x = fmaxf(fmaxf(m.x, w0*b2f(g0.x)), fmaxf(w1*b2f(g1.x), fmaxf(w2*b2f(g2.x), w3*b2f(g3.x))));
            m.y = fmaxf(fmaxf(m.y, w0*b2f(g0.y)), fmaxf(w1*b2f(g1.y), fmaxf(w2*b2f(g2.y), w3*b2f(g3.y))));
            m.z = fmaxf(fmaxf(m.z, w0*b2f(g0.z)), fmaxf(w1*b2f(g1.z), fmaxf(w2*b2f(g2.z), w3*b2f(g3.z))));
            m.w = fmaxf(fmaxf(m.w, w0*b2f(g0.w)), fmaxf(w1*b2f(g1.w), fmaxf(w2*b2f(g2.w), w3*b2f(g3.w))));
        }
    }
    for (; p < p1; p++){
        int2 e0 = sedge[p];
        if (act){
            ushort4 g0 = ((const ushort4*)(H2 + (size_t)e0.x * HID))[lane];
            float w0 = __int_as_float(e0.y);
            m.x = fmaxf(m.x, w0 * b2f(g0.x)); m.y = fmaxf(m.y, w0 * b2f(g0.y));
            m.z = fmaxf(m.z, w0 * b2f(g0.z)); m.w = fmaxf(m.w, w0 * b2f(g0.w));
        }
    }
    if (act){
        float4 b = ((const float4*)bias)[lane];
        float4 o;
        o.x = fmaxf(m.x + b.x, 0.0f);
        o.y = fmaxf(m.y + b.y, 0.0f);
        o.z = fmaxf(m.z + b.z, 0.0f);
        o.w = fmaxf(m.w + b.w, 0.0f);
        ((float4*)(out + (size_t)d * HID))[lane] = o;
    }
}

extern "C" void kernel_launch(void* const* d_in, const int* in_sizes, int n_in,
                              void* d_out, int out_size, void* d_ws, size_t ws_size,
                              hipStream_t stream){
    const float* x  = (const float*)d_in[0];
    const int*   ei = (const int*)  d_in[1];
    const float* ew = (const float*)d_in[2];
    const float* W1 = (const float*)d_in[3];
    const float* b1 = (const float*)d_in[4];
    const float* W2 = (const float*)d_in[5];
    const float* b2 = (const float*)d_in[6];
    const float* We = (const float*)d_in[7];
    const float* be = (const float*)d_in[8];
    float* out = (float*)d_out;

    const int N = in_sizes[0] / 5;
    const int E = in_sizes[2];
    const int* row = ei;
    const int* col = ei + E;
    const int nb = (N + 255) / 256;

    char* w = (char*)d_ws;
    size_t o = 0;
    auto alloc = [&](size_t bytes) -> void* {
        void* p = w + o;
        o = alignUp(o + bytes, 256);
        return p;
    };
    float*          dis   = (float*)          alloc((size_t)N * 4);
    unsigned*       cnt   = (unsigned*)       alloc((size_t)N * 4);
    unsigned*       poff  = (unsigned*)       alloc((size_t)(N + 1) * 4);
    unsigned*       cur   = (unsigned*)       alloc((size_t)N * 4);
    unsigned*       bsum  = (unsigned*)       alloc((size_t)nb * 4);
    unsigned*       boff  = (unsigned*)       alloc((size_t)nb * 4);
    int2*           sedge = (int2*)           alloc(((size_t)E + 32u * N + 64u) * 8);
    float*          xp    = (float*)          alloc((size_t)N * 8 * 4);
    unsigned short* W1f   = (unsigned short*) alloc((size_t)2 * 8 * 64 * 8 * 2);
    unsigned short* Bt2h  = (unsigned short*) alloc((size_t)256 * HID * 2);
    unsigned short* Bt2l  = (unsigned short*) alloc((size_t)256 * HID * 2);
    unsigned short* Bt3h  = (unsigned short*) alloc((size_t)128 * HID * 2);
    unsigned short* Bt3l  = (unsigned short*) alloc((size_t)128 * HID * 2);
    unsigned short* bufH2 = (unsigned short*) alloc((size_t)N * HID * 2);
    float*          bufB  = (float*)          alloc((size_t)N * HID * 4);
    (void)ws_size; (void)n_in; (void)out_size;

    int bn = nb;
    int be_ = (E + 255) / 256;

    // graph build + weight prep
    k_init    <<<bn, 256, 0, stream>>>(dis, cnt, N);
    k_deg_hist<<<be_, 256, 0, stream>>>(col, ew, dis, cnt, E);
    k_dis     <<<bn, 256, 0, stream>>>(dis, N);
    k_bsum    <<<bn, 256, 0, stream>>>(cnt, bsum, N);
    k_bscan   <<<1, 256, 0, stream>>>(bsum, boff, poff, nb, N);
    k_offs    <<<bn, 256, 0, stream>>>(cnt, boff, poff, cur, N);
    k_fill    <<<bn, 256, 0, stream>>>(cnt, poff, dis, sedge, N);
    k_scatter <<<be_, 256, 0, stream>>>(row, col, ew, dis, cur, sedge, E);
    k_prep_x  <<<bn, 256, 0, stream>>>(x, xp, N);
    k_prep_w1 <<<32, 256, 0, stream>>>(W1, W1f);
    k_prep_w  <<<(256 * HID + 255) / 256, 256, 0, stream>>>(W2, Bt2h, Bt2l, HID, HID, 256);
    k_prep_w  <<<(128 * HID + 255) / 256, 256, 0, stream>>>(We, Bt3h, Bt3l, HID, 80, 128);

    // layer 1: MFMA fused linear + max-agg + b1 + ReLU
    const int a1blocks = 768;                      // 3072 waves, ~16 dests/wave
    k_agg1m<<<a1blocks, 256, 0, stream>>>(xp, W1f, cnt, poff, sedge, b1, bufB, N, a1blocks * 4);

    // layer 2: split-bf16 MFMA GEMM -> bf16 rows, then bf16-gather max-agg + b2 + ReLU
    int gm = (N + 31) / 32;
    k_gemm_mfma<true><<<gm, 256, 0, stream>>>(bufB, Bt2h, Bt2l, nullptr, bufH2, N, HID, 256);
    k_aggb<<<(N + 3) / 4, 256, 0, stream>>>(bufH2, cnt, poff, sedge, b2, bufB, N);

    // readout: split-bf16 MFMA GEMM -> fp32 out + be
    k_gemm_mfma<false><<<gm, 256, 0, stream>>>(bufB, Bt3h, Bt3l, be, out, N, 80, 128);
}

// Round 8
// 565.246 us; speedup vs baseline: 1.7567x; 1.1267x over previous
//
#include <hip/hip_runtime.h>
#include <cfloat>

#define HID 240

static inline size_t alignUp(size_t x, size_t a){ return (x + a - 1) / a * a; }

typedef __bf16 bf16x8 __attribute__((ext_vector_type(8)));
typedef unsigned short u16x8 __attribute__((ext_vector_type(8)));
typedef float  f32x16 __attribute__((ext_vector_type(16)));

__device__ __forceinline__ float b2f(unsigned short u){
    return __uint_as_float(((unsigned)u) << 16);
}
__device__ __forceinline__ unsigned short f2b_rne(float f){
    unsigned r = __float_as_uint(f);
    r += 0x7FFFu + ((r >> 16) & 1u);
    return (unsigned short)(r >> 16);
}

// ---------------- init: packed (deg_fx | cnt) = 0 ----------------
__global__ void k_init(unsigned long long* __restrict__ pk, int N){
    int i = blockIdx.x * blockDim.x + threadIdx.x;
    if (i < N) pk[i] = 0ull;
}

// ---------------- degree + count in ONE 64-bit atomic per edge ----------------
// bits [0,40): sum of round(ew * 2^20)  (fixed-point, exact summation)
// bits [40,64): edge count
__global__ void k_deg_hist(const int* __restrict__ col, const float* __restrict__ ew,
                           unsigned long long* __restrict__ pk, int E){
    int e = blockIdx.x * blockDim.x + threadIdx.x;
    if (e < E){
        int c = col[e];
        unsigned q = __float2uint_rn(ew[e] * 1048576.0f);
        atomicAdd(&pk[c], (1ull << 40) | (unsigned long long)q);
    }
}

// ---------------- unpack: cnt, dis = rsqrt(1 + deg_fx * 2^-20) ----------------
__global__ void k_dis(const unsigned long long* __restrict__ pk,
                      float* __restrict__ dis, unsigned* __restrict__ cnt, int N){
    int i = blockIdx.x * blockDim.x + threadIdx.x;
    if (i < N){
        unsigned long long p = pk[i];
        cnt[i] = (unsigned)(p >> 40);
        float deg = 1.0f + (float)(p & 0xFFFFFFFFFFull) * (1.0f / 1048576.0f);
        dis[i] = rsqrtf(deg);
    }
}

// ---------------- pad x[N][5] -> xp[N][8] ----------------
__global__ void k_prep_x(const float* __restrict__ x, float* __restrict__ xp, int N){
    __shared__ float s[1280];
    int t = threadIdx.x;
    int rbase = blockIdx.x * 256;
    #pragma unroll
    for (int c = 0; c < 5; c++){
        int idx = rbase * 5 + t + 256 * c;
        s[t + 256 * c] = (idx < N * 5) ? x[idx] : 0.0f;
    }
    __syncthreads();
    #pragma unroll
    for (int c = 0; c < 8; c++){
        int pos = t + 256 * c;
        int r = pos >> 3, j = pos & 7;
        int grow = rbase + r;
        if (grow < N)
            xp[(size_t)grow * 8 + j] = (j < 5) ? s[r * 5 + j] : 0.0f;
    }
}

// ---------------- W1 (5x240) -> per-lane MFMA B-fragments ----------------
__global__ void k_prep_w1(const float* __restrict__ W1, unsigned short* __restrict__ W1f){
    int i = blockIdx.x * 256 + threadIdx.x;
    if (i < 2 * 8 * 64 * 8){
        int k    = i & 7;
        int lane = (i >> 3) & 63;
        int j    = (i >> 9) & 7;
        int s    = i >> 12;
        int lm = lane & 31, quad = lane >> 5;
        int kg = quad * 8 + k;
        int colm = 32 * j + lm;
        float v = (kg < 5 && colm < HID) ? W1[kg * HID + colm] : 0.0f;
        unsigned short hi = f2b_rne(v);
        W1f[i] = (s == 0) ? hi : f2b_rne(v - b2f(hi));
    }
}

// ---------------- split W[K][Ncol] into transposed bf16 hi/lo planes Bt[n][K] ----------------
__global__ void k_prep_w(const float* __restrict__ W, unsigned short* __restrict__ Bth,
                         unsigned short* __restrict__ Btl, int Kd, int Ncol, int Npad){
    int i = blockIdx.x * 256 + threadIdx.x;
    if (i < Npad * Kd){
        int n = i / Kd, k = i - n * Kd;
        float v = (n < Ncol) ? W[(size_t)k * Ncol + n] : 0.0f;
        unsigned short hi = f2b_rne(v);
        float lo = v - b2f(hi);
        Bth[i] = hi;
        Btl[i] = f2b_rne(lo);
    }
}

// ---------------- padded-CSR scan: per-block sums of chunk counts ----------------
__global__ void k_bsum(const unsigned* __restrict__ cnt, unsigned* __restrict__ bsum, int N){
    int b = blockIdx.x;
    int i = b * 256 + threadIdx.x;
    unsigned v = (i < N) ? ((cnt[i] + 32u) >> 5) : 0u;
    #pragma unroll
    for (int o = 32; o > 0; o >>= 1) v += __shfl_down(v, (unsigned)o, 64);
    __shared__ unsigned ws[4];
    int lane = threadIdx.x & 63, w = threadIdx.x >> 6;
    if (lane == 0) ws[w] = v;
    __syncthreads();
    if (threadIdx.x == 0) bsum[b] = ws[0] + ws[1] + ws[2] + ws[3];
}

// ---------------- scan of block sums (nb <= 256); also writes poff[N] ----------------
__global__ void k_bscan(const unsigned* __restrict__ bsum, unsigned* __restrict__ boff,
                        unsigned* __restrict__ poff, int nb, int N){
    __shared__ unsigned s[256];
    int t = threadIdx.x;
    unsigned v = (t < nb) ? bsum[t] : 0u;
    s[t] = v;
    __syncthreads();
    for (int o = 1; o < 256; o <<= 1){
        unsigned u = (t >= o) ? s[t - o] : 0u;
        __syncthreads();
        s[t] += u;
        __syncthreads();
    }
    if (t < nb) boff[t] = s[t] - v;
    if (t == 0) poff[N] = 32u * s[nb - 1];
}

// ---------------- final padded offsets; cur starts after the self slot ----------------
__global__ void k_offs(const unsigned* __restrict__ cnt, const unsigned* __restrict__ boff,
                       unsigned* __restrict__ poff, unsigned* __restrict__ cur, int N){
    int b = blockIdx.x, t = threadIdx.x;
    int i = b * 256 + t;
    unsigned v = (i < N) ? ((cnt[i] + 32u) >> 5) : 0u;
    int lane = t & 63, w = t >> 6;
    unsigned x = v;
    #pragma unroll
    for (int o = 1; o < 64; o <<= 1){
        unsigned u = __shfl_up(x, (unsigned)o, 64);
        if (lane >= o) x += u;
    }
    __shared__ unsigned ws[4];
    if (lane == 63) ws[w] = x;
    __syncthreads();
    unsigned wb = 0;
    if (w > 0) wb += ws[0];
    if (w > 1) wb += ws[1];
    if (w > 2) wb += ws[2];
    if (i < N){
        unsigned p = 32u * (boff[b] + wb + x - v);
        poff[i] = p;
        cur[i] = p + 1u;
    }
}

// ---------------- fill self-loop slot + tail padding with (d, dis^2) ----------------
__global__ void k_fill(const unsigned* __restrict__ cnt, const unsigned* __restrict__ poff,
                       const float* __restrict__ dis, int2* __restrict__ sedge, int N){
    int d = blockIdx.x * 256 + threadIdx.x;
    if (d < N){
        float dd = dis[d];
        int2 v = make_int2(d, __float_as_int(dd * dd));
        unsigned s0 = poff[d];
        unsigned s1 = poff[d + 1];
        sedge[s0] = v;
        for (unsigned s = s0 + 1u + cnt[d]; s < s1; s++) sedge[s] = v;
    }
}

// ---------------- scatter edges into padded CSR ----------------
__global__ void k_scatter(const int* __restrict__ row, const int* __restrict__ col,
                          const float* __restrict__ ew, const float* __restrict__ dis,
                          unsigned* __restrict__ cur, int2* __restrict__ sedge, int E){
    int e = blockIdx.x * blockDim.x + threadIdx.x;
    if (e < E){
        int r = row[e], c = col[e];
        float nw = dis[r] * ew[e] * dis[c];
        unsigned p = atomicAdd(&cur[c], 1u);
        sedge[p] = make_int2(r, __float_as_int(nw));
    }
}

// ---------------- layer-1 fused linear+max-agg via MFMA ----------------
__global__ __launch_bounds__(256) void k_agg1m(const float* __restrict__ xp,
                                               const unsigned short* __restrict__ W1f,
                                               const unsigned* __restrict__ cnt,
                                               const unsigned* __restrict__ poff,
                                               const int2* __restrict__ sedge,
                                               const float* __restrict__ bias,
                                               float* __restrict__ out, int N, int nwaves){
    int wid  = blockIdx.x * 4 + (threadIdx.x >> 6);
    int lane = threadIdx.x & 63;
    int lm   = lane & 31;

    bf16x8 bh[8], bl[8];
    #pragma unroll
    for (int j = 0; j < 8; j++){
        bh[j] = *(const bf16x8*)(W1f + ((size_t)(0 * 8 + j) * 64 + lane) * 8);
        bl[j] = *(const bf16x8*)(W1f + ((size_t)(1 * 8 + j) * 64 + lane) * 8);
    }
    float bv[8];
    #pragma unroll
    for (int j = 0; j < 8; j++){
        int c = 32 * j + lm;
        bv[j] = (c < HID) ? bias[c] : 0.0f;
    }
    const f32x16 zv = {};

    for (int d = wid; d < N; d += nwaves){
        unsigned base = poff[d];
        unsigned nch  = (cnt[d] + 32u) >> 5;
        float m[8];
        #pragma unroll
        for (int j = 0; j < 8; j++) m[j] = -FLT_MAX;

        for (unsigned c = 0; c < nch; c++){
            u16x8 ahu = (u16x8)0, alu = (u16x8)0;
            if (lane < 32){
                int2 e = sedge[base + 32u * c + (unsigned)lm];
                float w = __int_as_float(e.y);
                const float4* xr = (const float4*)(xp + (size_t)e.x * 8);
                float4 x0 = xr[0], x1 = xr[1];
                float p[5] = {w * x0.x, w * x0.y, w * x0.z, w * x0.w, w * x1.x};
                #pragma unroll
                for (int k = 0; k < 5; k++){
                    unsigned short h = f2b_rne(p[k]);
                    ahu[k] = h;
                    alu[k] = f2b_rne(p[k] - b2f(h));
                }
            }
            bf16x8 ah = __builtin_bit_cast(bf16x8, ahu);
            bf16x8 al = __builtin_bit_cast(bf16x8, alu);
            #pragma unroll
            for (int j = 0; j < 8; j += 2){
                f32x16 a0 = __builtin_amdgcn_mfma_f32_32x32x16_bf16(ah, bh[j],     zv, 0, 0, 0);
                f32x16 a1 = __builtin_amdgcn_mfma_f32_32x32x16_bf16(ah, bh[j + 1], zv, 0, 0, 0);
                a0 = __builtin_amdgcn_mfma_f32_32x32x16_bf16(ah, bl[j],     a0, 0, 0, 0);
                a1 = __builtin_amdgcn_mfma_f32_32x32x16_bf16(ah, bl[j + 1], a1, 0, 0, 0);
                a0 = __builtin_amdgcn_mfma_f32_32x32x16_bf16(al, bh[j],     a0, 0, 0, 0);
                a1 = __builtin_amdgcn_mfma_f32_32x32x16_bf16(al, bh[j + 1], a1, 0, 0, 0);
                #pragma unroll
                for (int r = 0; r < 16; r++){
                    m[j]     = fmaxf(m[j],     a0[r]);
                    m[j + 1] = fmaxf(m[j + 1], a1[r]);
                }
            }
        }
        float o[8];
        #pragma unroll
        for (int j = 0; j < 8; j++){
            float other = __shfl_xor(m[j], 32, 64);
            o[j] = fmaxf(fmaxf(m[j], other) + bv[j], 0.0f);
        }
        if (lane < 32){
            float* orow = out + (size_t)d * HID;
            #pragma unroll
            for (int j = 0; j < 8; j++){
                int c = 32 * j + lm;
                if (c < HID) orow[c] = o[j];
            }
        }
    }
}

// ---------------- split-bf16 MFMA GEMM: C = A(M x 240) @ W(240 x Ncol) ----------------
template <bool OB16>
__global__ __launch_bounds__(256) void k_gemm_mfma(const float* __restrict__ A,
                                                   const unsigned short* __restrict__ Bth,
                                                   const unsigned short* __restrict__ Btl,
                                                   const float* __restrict__ bias,
                                                   void* __restrict__ Cv,
                                                   int M, int Ncol, int Npad){
    __shared__ unsigned short As_hi[32][24];
    __shared__ unsigned short As_lo[32][24];
    const int K = 240;
    int t = threadIdx.x;
    int wave = t >> 6, lane = t & 63;
    int m0 = blockIdx.x * 32;
    int n0 = wave * 64;
    bool wact = n0 < Npad;

    int lm   = lane & 31;
    int quad = lane >> 5;

    f32x16 acc0 = {};
    f32x16 acc1 = {};

    for (int k0 = 0; k0 < K; k0 += 16){
        if (t < 128){
            int m = t >> 2, kq = (t & 3) * 4;
            float4 av = make_float4(0.f, 0.f, 0.f, 0.f);
            if (m0 + m < M) av = *(const float4*)(A + (size_t)(m0 + m) * K + k0 + kq);
            ushort4 hi, lo;
            hi.x = f2b_rne(av.x); lo.x = f2b_rne(av.x - b2f(hi.x));
            hi.y = f2b_rne(av.y); lo.y = f2b_rne(av.y - b2f(hi.y));
            hi.z = f2b_rne(av.z); lo.z = f2b_rne(av.z - b2f(hi.z));
            hi.w = f2b_rne(av.w); lo.w = f2b_rne(av.w - b2f(hi.w));
            *(ushort4*)&As_hi[m][kq] = hi;
            *(ushort4*)&As_lo[m][kq] = lo;
        }
        __syncthreads();
        if (wact){
            bf16x8 ah = *(const bf16x8*)&As_hi[lm][quad * 8];
            bf16x8 al = *(const bf16x8*)&As_lo[lm][quad * 8];
            size_t bo0 = (size_t)(n0 + lm) * K + k0 + quad * 8;
            size_t bo1 = (size_t)(n0 + 32 + lm) * K + k0 + quad * 8;
            bf16x8 bh0 = *(const bf16x8*)(Bth + bo0);
            bf16x8 bl0 = *(const bf16x8*)(Btl + bo0);
            bf16x8 bh1 = *(const bf16x8*)(Bth + bo1);
            bf16x8 bl1 = *(const bf16x8*)(Btl + bo1);
            acc0 = __builtin_amdgcn_mfma_f32_32x32x16_bf16(ah, bh0, acc0, 0, 0, 0);
            acc0 = __builtin_amdgcn_mfma_f32_32x32x16_bf16(ah, bl0, acc0, 0, 0, 0);
            acc0 = __builtin_amdgcn_mfma_f32_32x32x16_bf16(al, bh0, acc0, 0, 0, 0);
            acc1 = __builtin_amdgcn_mfma_f32_32x32x16_bf16(ah, bh1, acc1, 0, 0, 0);
            acc1 = __builtin_amdgcn_mfma_f32_32x32x16_bf16(ah, bl1, acc1, 0, 0, 0);
            acc1 = __builtin_amdgcn_mfma_f32_32x32x16_bf16(al, bh1, acc1, 0, 0, 0);
        }
        __syncthreads();
    }

    if (!wact) return;
    #pragma unroll
    for (int h = 0; h < 2; h++){
        int n = n0 + 32 * h + lm;
        if (n >= Ncol) continue;
        float bvv = (!OB16 && bias) ? bias[n] : 0.0f;
        #pragma unroll
        for (int r = 0; r < 16; r++){
            int m = m0 + (r & 3) + 8 * (r >> 2) + 4 * quad;
            if (m >= M) continue;
            float v = (h == 0) ? acc0[r] : acc1[r];
            if (OB16){
                ((unsigned short*)Cv)[(size_t)m * Ncol + n] = f2b_rne(v);
            } else {
                ((float*)Cv)[(size_t)m * Ncol + n] = v + bvv;
            }
        }
    }
}

// ---------------- layer-2 scatter-max over bf16 rows (self slot included), +bias, ReLU ----------------
__global__ __launch_bounds__(256) void k_aggb(const unsigned short* __restrict__ H2,
                                              const unsigned* __restrict__ cnt,
                                              const unsigned* __restrict__ poff,
                                              const int2* __restrict__ sedge,
                                              const float* __restrict__ bias,
                                              float* __restrict__ out, int N){
    int d    = blockIdx.x * 4 + (threadIdx.x >> 6);
    int lane = threadIdx.x & 63;
    if (d >= N) return;
    bool act = lane < 60;

    float4 m = make_float4(-FLT_MAX, -FLT_MAX, -FLT_MAX, -FLT_MAX);
    unsigned p0 = poff[d], p1 = p0 + 1u + cnt[d];
    unsigned p = p0;
    for (; p + 4 <= p1; p += 4){
        int2 e0 = sedge[p], e1 = sedge[p+1], e2 = sedge[p+2], e3 = sedge[p+3];
        if (act){
            ushort4 g0 = ((const ushort4*)(H2 + (size_t)e0.x * HID))[lane];
            ushort4 g1 = ((const ushort4*)(H2 + (size_t)e1.x * HID))[lane];
            ushort4 g2 = ((const ushort4*)(H2 + (size_t)e2.x * HID))[lane];
            ushort4 g3 = ((const ushort4*)(H2 + (size_t)e3.x * HID))[lane];
            float w0 = __int_as_float(e0.y), w1 = __int_as_float(e1.y);
            float w2 = __int_as_float(e2.y), w3 = __int_as_float(e3.y);
            m.x = fmaxf(fmaxf(m.x, w0*b2f(g0.x)), fmaxf(w1*b2f(g1.x), fmaxf(w2*b2f(g2.x), w3*b2f(g3.x))));
            m.y = fmaxf(fmaxf(m.y, w0*b2f(g0.y)), fmaxf(w1*b2f(g1.y), fmaxf(w2*b2f(g2.y), w3*b2f(g3.y))));
            m.z = fmaxf(fmaxf(m.z, w0*b2f(g0.z)), fmaxf(w1*b2f(g1.z), fmaxf(w2*b2f(g2.z), w3*b2f(g3.z))));
            m.w = fmaxf(fmaxf(m.w, w0*b2f(g0.w)), fmaxf(w1*b2f(g1.w), fmaxf(w2*b2f(g2.w), w3*b2f(g3.w))));
        }
    }
    for (; p < p1; p++){
        int2 e0 = sedge[p];
        if (act){
            ushort4 g0 = ((const ushort4*)(H2 + (size_t)e0.x * HID))[lane];
            float w0 = __int_as_float(e0.y);
            m.x = fmaxf(m.x, w0 * b2f(g0.x)); m.y = fmaxf(m.y, w0 * b2f(g0.y));
            m.z = fmaxf(m.z, w0 * b2f(g0.z)); m.w = fmaxf(m.w, w0 * b2f(g0.w));
        }
    }
    if (act){
        float4 b = ((const float4*)bias)[lane];
        float4 o;
        o.x = fmaxf(m.x + b.x, 0.0f);
        o.y = fmaxf(m.y + b.y, 0.0f);
        o.z = fmaxf(m.z + b.z, 0.0f);
        o.w = fmaxf(m.w + b.w, 0.0f);
        ((float4*)(out + (size_t)d * HID))[lane] = o;
    }
}

extern "C" void kernel_launch(void* const* d_in, const int* in_sizes, int n_in,
                              void* d_out, int out_size, void* d_ws, size_t ws_size,
                              hipStream_t stream){
    const float* x  = (const float*)d_in[0];
    const int*   ei = (const int*)  d_in[1];
    const float* ew = (const float*)d_in[2];
    const float* W1 = (const float*)d_in[3];
    const float* b1 = (const float*)d_in[4];
    const float* W2 = (const float*)d_in[5];
    const float* b2 = (const float*)d_in[6];
    const float* We = (const float*)d_in[7];
    const float* be = (const float*)d_in[8];
    float* out = (float*)d_out;

    const int N = in_sizes[0] / 5;
    const int E = in_sizes[2];
    const int* row = ei;
    const int* col = ei + E;
    const int nb = (N + 255) / 256;

    char* w = (char*)d_ws;
    size_t o = 0;
    auto alloc = [&](size_t bytes) -> void* {
        void* p = w + o;
        o = alignUp(o + bytes, 256);
        return p;
    };
    unsigned long long* pk = (unsigned long long*) alloc((size_t)N * 8);
    float*          dis   = (float*)          alloc((size_t)N * 4);
    unsigned*       cnt   = (unsigned*)       alloc((size_t)N * 4);
    unsigned*       poff  = (unsigned*)       alloc((size_t)(N + 1) * 4);
    unsigned*       cur   = (unsigned*)       alloc((size_t)N * 4);
    unsigned*       bsum  = (unsigned*)       alloc((size_t)nb * 4);
    unsigned*       boff  = (unsigned*)       alloc((size_t)nb * 4);
    int2*           sedge = (int2*)           alloc(((size_t)E + 32u * N + 64u) * 8);
    float*          xp    = (float*)          alloc((size_t)N * 8 * 4);
    unsigned short* W1f   = (unsigned short*) alloc((size_t)2 * 8 * 64 * 8 * 2);
    unsigned short* Bt2h  = (unsigned short*) alloc((size_t)256 * HID * 2);
    unsigned short* Bt2l  = (unsigned short*) alloc((size_t)256 * HID * 2);
    unsigned short* Bt3h  = (unsigned short*) alloc((size_t)128 * HID * 2);
    unsigned short* Bt3l  = (unsigned short*) alloc((size_t)128 * HID * 2);
    unsigned short* bufH2 = (unsigned short*) alloc((size_t)N * HID * 2);
    float*          bufB  = (float*)          alloc((size_t)N * HID * 4);
    (void)ws_size; (void)n_in; (void)out_size;

    int bn = nb;
    int be_ = (E + 255) / 256;

    // graph build + weight prep
    k_init    <<<bn, 256, 0, stream>>>(pk, N);
    k_deg_hist<<<be_, 256, 0, stream>>>(col, ew, pk, E);
    k_dis     <<<bn, 256, 0, stream>>>(pk, dis, cnt, N);
    k_bsum    <<<bn, 256, 0, stream>>>(cnt, bsum, N);
    k_bscan   <<<1, 256, 0, stream>>>(bsum, boff, poff, nb, N);
    k_offs    <<<bn, 256, 0, stream>>>(cnt, boff, poff, cur, N);
    k_fill    <<<bn, 256, 0, stream>>>(cnt, poff, dis, sedge, N);
    k_scatter <<<be_, 256, 0, stream>>>(row, col, ew, dis, cur, sedge, E);
    k_prep_x  <<<bn, 256, 0, stream>>>(x, xp, N);
    k_prep_w1 <<<32, 256, 0, stream>>>(W1, W1f);
    k_prep_w  <<<(256 * HID + 255) / 256, 256, 0, stream>>>(W2, Bt2h, Bt2l, HID, HID, 256);
    k_prep_w  <<<(128 * HID + 255) / 256, 256, 0, stream>>>(We, Bt3h, Bt3l, HID, 80, 128);

    // layer 1: MFMA fused linear + max-agg + b1 + ReLU
    const int a1blocks = 768;
    k_agg1m<<<a1blocks, 256, 0, stream>>>(xp, W1f, cnt, poff, sedge, b1, bufB, N, a1blocks * 4);

    // layer 2: split-bf16 MFMA GEMM -> bf16 rows, then bf16-gather max-agg + b2 + ReLU
    int gm = (N + 31) / 32;
    k_gemm_mfma<true><<<gm, 256, 0, stream>>>(bufB, Bt2h, Bt2l, nullptr, bufH2, N, HID, 256);
    k_aggb<<<(N + 3) / 4, 256, 0, stream>>>(bufH2, cnt, poff, sedge, b2, bufB, N);

    // readout: split-bf16 MFMA GEMM -> fp32 out + be
    k_gemm_mfma<false><<<gm, 256, 0, stream>>>(bufB, Bt3h, Bt3l, be, out, N, 80, 128);
}